// Round 2
// baseline (1015.529 us; speedup 1.0000x reference)
//
#include <hip/hip_runtime.h>
#include <hip/hip_bf16.h>

// Problem constants (from reference)
#define NN   2048      // B*S nodes
#define BB   16
#define SS   128
#define HH   256       // hidden
#define DE   192
#define DR   64
#define DIN  256
#define LOUT 12
#define NLEV 21

typedef __hip_bfloat16 bf16;
__device__ __forceinline__ float sigm(float x){ return 1.f/(1.f + __expf(-x)); }

// dtype-generic scalar weight load
template<typename T> __device__ __forceinline__ float ldw(const T* p, long long i);
template<> __device__ __forceinline__ float ldw<float>(const float* p, long long i){ return p[i]; }
template<> __device__ __forceinline__ float ldw<bf16>(const bf16* p, long long i){ return __bfloat162float(p[i]); }

// ---------------------------------------------------------------------------
// Probe: decide whether float arrays are bf16 or fp32.
// emb_W ~ U(-0.08, 0.08). If bf16: low 16 bits of each dword are a bf16 with
// |v| <= 0.125 (always). If fp32: low 16 bits are mantissa bits (random);
// P(all 64 decode small) ~ 1e-20. flag=1 => bf16.
// ---------------------------------------------------------------------------
__global__ void probe_dtype(const unsigned int* __restrict__ emb, int* __restrict__ flag)
{
    if (threadIdx.x == 0 && blockIdx.x == 0) {
        int all_small = 1;
        for (int i = 0; i < 64; ++i) {
            unsigned int u = emb[i];
            float f = __uint_as_float((u & 0xFFFFu) << 16);
            if (!(fabsf(f) <= 0.125f)) all_small = 0;
        }
        flag[0] = all_small;
    }
}

// ---------------------------------------------------------------------------
// Setup: build CSR children adjacency from (child_idx, parent_idx) edge list.
// ---------------------------------------------------------------------------
__global__ __launch_bounds__(256) void build_children(
    const int* __restrict__ child_idx, const int* __restrict__ parent_idx,
    int E, int* __restrict__ ch_off, int* __restrict__ ch_list)
{
    __shared__ int cnt[NN];
    __shared__ int cur[NN];
    __shared__ int partial[256];
    const int t = threadIdx.x;

    for (int i = t; i < NN; i += 256) cnt[i] = 0;
    __syncthreads();
    for (int e = t; e < E; e += 256) atomicAdd(&cnt[parent_idx[e]], 1);
    __syncthreads();

    int s = 0;
    #pragma unroll
    for (int j = 0; j < 8; ++j) s += cnt[t*8 + j];
    partial[t] = s;
    __syncthreads();
    for (int off = 1; off < 256; off <<= 1) {
        int v = (t >= off) ? partial[t - off] : 0;
        __syncthreads();
        partial[t] += v;
        __syncthreads();
    }
    int run = (t == 0) ? 0 : partial[t - 1];
    int offs[8];
    #pragma unroll
    for (int j = 0; j < 8; ++j) { offs[j] = run; run += cnt[t*8 + j]; }
    __syncthreads();
    #pragma unroll
    for (int j = 0; j < 8; ++j) { int idx = t*8 + j; cnt[idx] = offs[j]; cur[idx] = offs[j]; }
    __syncthreads();

    for (int e = t; e < E; e += 256) {
        int p = parent_idx[e];
        int pos = atomicAdd(&cur[p], 1);
        ch_list[pos] = child_idx[e];
    }
    for (int i = t; i < NN; i += 256) ch_off[i] = cnt[i];
    if (t == 0) ch_off[NN] = E;
}

// ---------------------------------------------------------------------------
// Phase 1 body: ix/fx/ox/ux = concat(emb,rel) @ W_* (+ b_*); 8 nodes/block.
// ---------------------------------------------------------------------------
template<typename T>
__device__ __forceinline__ void phase1_body(
    float (*xc)[DIN],
    const int* __restrict__ xs, const int* __restrict__ rels,
    const T* __restrict__ emb_W, const T* __restrict__ rel_W,
    const T* __restrict__ W_ix, const T* __restrict__ b_ix,
    const T* __restrict__ W_fx, const T* __restrict__ b_fx,
    const T* __restrict__ W_ox, const T* __restrict__ W_ux,
    float* __restrict__ ix, float* __restrict__ fx,
    float* __restrict__ ox, float* __restrict__ ux)
{
    const int t = threadIdx.x;
    const int node0 = blockIdx.x * 8;

    #pragma unroll
    for (int j = 0; j < 8; ++j) {
        int n = node0 + j;
        if (t < DE) {
            long long w = (long long)xs[n];
            xc[j][t] = ldw(emb_W, w * DE + t);
        } else {
            long long r = (long long)rels[n];
            xc[j][t] = ldw(rel_W, r * DR + (t - DE));
        }
    }
    __syncthreads();

    float ai[8], af[8], ao[8], au[8];
    const float bi  = ldw(b_ix, t);
    const float bfv = ldw(b_fx, t);
    #pragma unroll
    for (int j = 0; j < 8; ++j) { ai[j] = bi; af[j] = bfv; ao[j] = 0.f; au[j] = 0.f; }

    for (int k = 0; k < DIN; k += 4) {
        float wi[4], wf[4], wo[4], wu[4];
        #pragma unroll
        for (int q = 0; q < 4; ++q) {
            wi[q] = ldw(W_ix, (long long)(k+q)*HH + t);
            wf[q] = ldw(W_fx, (long long)(k+q)*HH + t);
            wo[q] = ldw(W_ox, (long long)(k+q)*HH + t);
            wu[q] = ldw(W_ux, (long long)(k+q)*HH + t);
        }
        #pragma unroll
        for (int j = 0; j < 8; ++j) {
            float4 xv = *(const float4*)&xc[j][k];
            ai[j] += xv.x*wi[0] + xv.y*wi[1] + xv.z*wi[2] + xv.w*wi[3];
            af[j] += xv.x*wf[0] + xv.y*wf[1] + xv.z*wf[2] + xv.w*wf[3];
            ao[j] += xv.x*wo[0] + xv.y*wo[1] + xv.z*wo[2] + xv.w*wo[3];
            au[j] += xv.x*wu[0] + xv.y*wu[1] + xv.z*wu[2] + xv.w*wu[3];
        }
    }
    #pragma unroll
    for (int j = 0; j < 8; ++j) {
        int n = node0 + j;
        ix[n*HH + t] = ai[j];
        fx[n*HH + t] = af[j];
        ox[n*HH + t] = ao[j];
        ux[n*HH + t] = au[j];
    }
}

__global__ __launch_bounds__(256) void phase1_k(
    const int* __restrict__ flag,
    const int* __restrict__ xs, const int* __restrict__ rels,
    const void* emb_W, const void* rel_W,
    const void* W_ix, const void* b_ix,
    const void* W_fx, const void* b_fx,
    const void* W_ox, const void* W_ux,
    float* ix, float* fx, float* ox, float* ux)
{
    __shared__ float xc[8][DIN];
    if (*flag) {
        phase1_body<bf16>(xc, xs, rels, (const bf16*)emb_W, (const bf16*)rel_W,
            (const bf16*)W_ix, (const bf16*)b_ix, (const bf16*)W_fx, (const bf16*)b_fx,
            (const bf16*)W_ox, (const bf16*)W_ux, ix, fx, ox, ux);
    } else {
        phase1_body<float>(xc, xs, rels, (const float*)emb_W, (const float*)rel_W,
            (const float*)W_ix, (const float*)b_ix, (const float*)W_fx, (const float*)b_fx,
            (const float*)W_ox, (const float*)W_ux, ix, fx, ox, ux);
    }
}

// ---------------------------------------------------------------------------
// One bottom-up level. Block n handles node n iff height(n)==level.
// ---------------------------------------------------------------------------
template<typename T>
__device__ __forceinline__ void level_body(
    float (*hch)[HH], float* hs, int* chs,
    int level,
    const int* __restrict__ node_height,
    const int* __restrict__ ch_off, const int* __restrict__ ch_list,
    const T* __restrict__ W_ih, const T* __restrict__ b_ih,
    const T* __restrict__ W_fh, const T* __restrict__ b_fh,
    const T* __restrict__ W_oh, const T* __restrict__ W_uh,
    const float* __restrict__ ix, const float* __restrict__ fx,
    const float* __restrict__ ox, const float* __restrict__ ux,
    float* __restrict__ h, float* __restrict__ c)
{
    const int n = blockIdx.x;
    if (node_height[n] != level) return;
    const int t = threadIdx.x;
    const int off = ch_off[n];
    const int cnt = ch_off[n+1] - off;

    float h_sum = 0.f, fc = 0.f;
    const float fxn = fx[n*HH + t];
    const float bfh = ldw(b_fh, t);

    for (int base = 0; base < cnt; base += 4) {
        int m = cnt - base; if (m > 4) m = 4;
        if (t < m) chs[t] = ch_list[off + base + t];
        __syncthreads();
        for (int j = 0; j < m; ++j) {
            float v = h[chs[j]*HH + t];
            hch[j][t] = v;
            h_sum += v;
        }
        __syncthreads();
        float d[4] = {0.f, 0.f, 0.f, 0.f};
        for (int k = 0; k < HH; k += 4) {
            float wf0 = ldw(W_fh, (long long)(k+0)*HH + t);
            float wf1 = ldw(W_fh, (long long)(k+1)*HH + t);
            float wf2 = ldw(W_fh, (long long)(k+2)*HH + t);
            float wf3 = ldw(W_fh, (long long)(k+3)*HH + t);
            for (int j = 0; j < m; ++j) {
                float4 hv = *(const float4*)&hch[j][k];
                d[j] += hv.x*wf0 + hv.y*wf1 + hv.z*wf2 + hv.w*wf3;
            }
        }
        for (int j = 0; j < m; ++j) {
            float f = sigm(d[j] + bfh + fxn);
            fc += f * c[chs[j]*HH + t];
        }
        __syncthreads();   // protect hch/chs before next tile
    }

    hs[t] = h_sum;
    __syncthreads();

    float di = 0.f, dof = 0.f, du = 0.f;
    if (cnt > 0) {
        for (int k = 0; k < HH; k += 4) {
            float4 hv = *(const float4*)&hs[k];
            float wi0 = ldw(W_ih,(long long)(k+0)*HH+t), wi1 = ldw(W_ih,(long long)(k+1)*HH+t);
            float wi2 = ldw(W_ih,(long long)(k+2)*HH+t), wi3 = ldw(W_ih,(long long)(k+3)*HH+t);
            float wo0 = ldw(W_oh,(long long)(k+0)*HH+t), wo1 = ldw(W_oh,(long long)(k+1)*HH+t);
            float wo2 = ldw(W_oh,(long long)(k+2)*HH+t), wo3 = ldw(W_oh,(long long)(k+3)*HH+t);
            float wu0 = ldw(W_uh,(long long)(k+0)*HH+t), wu1 = ldw(W_uh,(long long)(k+1)*HH+t);
            float wu2 = ldw(W_uh,(long long)(k+2)*HH+t), wu3 = ldw(W_uh,(long long)(k+3)*HH+t);
            di  += hv.x*wi0 + hv.y*wi1 + hv.z*wi2 + hv.w*wi3;
            dof += hv.x*wo0 + hv.y*wo1 + hv.z*wo2 + hv.w*wo3;
            du  += hv.x*wu0 + hv.y*wu1 + hv.z*wu2 + hv.w*wu3;
        }
    }
    float iv = sigm(ix[n*HH + t] + di + ldw(b_ih, t));
    float ov = sigm(ox[n*HH + t] + dof);
    float uv = tanhf(ux[n*HH + t] + du);
    float cv = iv * uv + fc;
    float hv = ov * tanhf(cv);
    h[n*HH + t] = hv;
    c[n*HH + t] = cv;
}

__global__ __launch_bounds__(256) void level_k(
    const int* __restrict__ flag, int level,
    const int* __restrict__ node_height,
    const int* __restrict__ ch_off, const int* __restrict__ ch_list,
    const void* W_ih, const void* b_ih, const void* W_fh, const void* b_fh,
    const void* W_oh, const void* W_uh,
    const float* ix, const float* fx, const float* ox, const float* ux,
    float* h, float* c)
{
    __shared__ float hch[4][HH];
    __shared__ float hs[HH];
    __shared__ int   chs[4];
    if (*flag) {
        level_body<bf16>(hch, hs, chs, level, node_height, ch_off, ch_list,
            (const bf16*)W_ih, (const bf16*)b_ih, (const bf16*)W_fh, (const bf16*)b_fh,
            (const bf16*)W_oh, (const bf16*)W_uh, ix, fx, ox, ux, h, c);
    } else {
        level_body<float>(hch, hs, chs, level, node_height, ch_off, ch_list,
            (const float*)W_ih, (const float*)b_ih, (const float*)W_fh, (const float*)b_fh,
            (const float*)W_oh, (const float*)W_uh, ix, fx, ox, ux, h, c);
    }
}

// ---------------------------------------------------------------------------
// Max-pool over sequence + [256 x 12] output projection.
// ---------------------------------------------------------------------------
template<typename T>
__device__ __forceinline__ void pool_body(
    float* pl, const float* __restrict__ h,
    const T* __restrict__ W_out, const T* __restrict__ b_out,
    void* out, int out_is_bf16)
{
    const int b = blockIdx.x, t = threadIdx.x;
    float m = -1e30f;
    for (int s = 0; s < SS; ++s) m = fmaxf(m, h[(b*SS + s)*HH + t]);
    pl[t] = m;
    __syncthreads();
    if (t < LOUT) {
        float acc = ldw(b_out, t);
        for (int j = 0; j < HH; ++j) acc += pl[j] * ldw(W_out, (long long)j*LOUT + t);
        if (out_is_bf16) ((bf16*)out)[b*LOUT + t] = __float2bfloat16(acc);
        else             ((float*)out)[b*LOUT + t] = acc;
    }
}

__global__ __launch_bounds__(256) void pool_k(
    const int* __restrict__ flag, const float* h,
    const void* W_out, const void* b_out, void* out)
{
    __shared__ float pl[HH];
    if (*flag) pool_body<bf16>(pl, h, (const bf16*)W_out, (const bf16*)b_out, out, 1);
    else       pool_body<float>(pl, h, (const float*)W_out, (const float*)b_out, out, 0);
}

// ---------------------------------------------------------------------------
extern "C" void kernel_launch(void* const* d_in, const int* in_sizes, int n_in,
                              void* d_out, int out_size, void* d_ws, size_t ws_size,
                              hipStream_t stream)
{
    const int*  xs          = (const int*)d_in[0];
    const int*  rels        = (const int*)d_in[1];
    const int*  child_idx   = (const int*)d_in[2];
    const int*  parent_idx  = (const int*)d_in[3];
    const int*  node_height = (const int*)d_in[4];
    // d_in[5] = n_levels (==21, hardcoded as NLEV)
    const void* emb_W = d_in[6];
    const void* rel_W = d_in[7];
    const void* W_ix  = d_in[8];
    const void* b_ix  = d_in[9];
    const void* W_ih  = d_in[10];
    const void* b_ih  = d_in[11];
    const void* W_fx  = d_in[12];
    const void* b_fx  = d_in[13];
    const void* W_fh  = d_in[14];
    const void* b_fh  = d_in[15];
    const void* W_ox  = d_in[16];
    const void* W_oh  = d_in[17];
    const void* W_ux  = d_in[18];
    const void* W_uh  = d_in[19];
    const void* W_out = d_in[20];
    const void* b_out = d_in[21];
    const int E = in_sizes[2];   // 2032 edges

    // workspace layout
    const size_t NH = (size_t)NN * HH;
    float* ix = (float*)d_ws;
    float* fx = ix + NH;
    float* ox = fx + NH;
    float* ux = ox + NH;
    float* h  = ux + NH;
    float* c  = h  + NH;
    int* ch_off  = (int*)(c + NH);          // NN+1
    int* ch_list = ch_off + (NN + 4);       // E entries
    int* flag    = ch_list + E + 4;

    probe_dtype<<<1, 64, 0, stream>>>((const unsigned int*)emb_W, flag);
    build_children<<<1, 256, 0, stream>>>(child_idx, parent_idx, E, ch_off, ch_list);
    phase1_k<<<NN/8, 256, 0, stream>>>(flag, xs, rels, emb_W, rel_W,
                                       W_ix, b_ix, W_fx, b_fx, W_ox, W_ux,
                                       ix, fx, ox, ux);
    for (int lev = 0; lev < NLEV; ++lev) {
        level_k<<<NN, 256, 0, stream>>>(flag, lev, node_height, ch_off, ch_list,
                                        W_ih, b_ih, W_fh, b_fh, W_oh, W_uh,
                                        ix, fx, ox, ux, h, c);
    }
    pool_k<<<BB, 256, 0, stream>>>(flag, h, W_out, b_out, d_out);
}

// Round 3
// 869.335 us; speedup vs baseline: 1.1682x; 1.1682x over previous
//
#include <hip/hip_runtime.h>
#include <hip/hip_bf16.h>
#include <hip/hip_cooperative_groups.h>

namespace cg = cooperative_groups;

// Problem constants (from reference)
#define NN   2048      // B*S nodes
#define BB   16
#define SS   128
#define HH   256       // hidden
#define DE   192
#define DR   64
#define DIN  256
#define LOUT 12
#define NLEV 21

#define CPAD  260      // padded K stride (multiple of 4 for float4, odd/4 for banks)
#define WCOLS 32       // columns per block (8 col-groups x 32 = 256)

typedef __hip_bfloat16 bf16;
__device__ __forceinline__ float sigm(float x){ return 1.f/(1.f + __expf(-x)); }

// dtype-generic scalar weight load
template<typename T> __device__ __forceinline__ float ldw(const T* p, long long i);
template<> __device__ __forceinline__ float ldw<float>(const float* p, long long i){ return p[i]; }
template<> __device__ __forceinline__ float ldw<bf16>(const bf16* p, long long i){ return __bfloat162float(p[i]); }

// ---------------------------------------------------------------------------
// Probe: bf16 vs fp32 detection (emb_W ~ U(-0.08,0.08); see round-1 notes).
// flag=1 => bf16.
// ---------------------------------------------------------------------------
__global__ void probe_dtype(const unsigned int* __restrict__ emb, int* __restrict__ flag)
{
    if (threadIdx.x == 0 && blockIdx.x == 0) {
        int all_small = 1;
        for (int i = 0; i < 64; ++i) {
            unsigned int u = emb[i];
            float f = __uint_as_float((u & 0xFFFFu) << 16);
            if (!(fabsf(f) <= 0.125f)) all_small = 0;
        }
        flag[0] = all_small;
    }
}

// ---------------------------------------------------------------------------
// Setup: CSR children adjacency + per-level node lists + max height.
// Single block.
// ---------------------------------------------------------------------------
__global__ __launch_bounds__(256) void setup_k(
    const int* __restrict__ child_idx, const int* __restrict__ parent_idx,
    const int* __restrict__ node_height, int E,
    int* __restrict__ ch_off, int* __restrict__ ch_list,
    int* __restrict__ lev_off, int* __restrict__ lev_nodes, int* __restrict__ maxH)
{
    __shared__ int cnt[NN];
    __shared__ int cur[NN];
    __shared__ int partial[256];
    __shared__ int lc[NLEV];
    __shared__ int lcur[NLEV];
    __shared__ int mh;
    const int t = threadIdx.x;

    for (int i = t; i < NN; i += 256) cnt[i] = 0;
    if (t < NLEV) lc[t] = 0;
    if (t == 0) mh = 0;
    __syncthreads();
    for (int e = t; e < E; e += 256) atomicAdd(&cnt[parent_idx[e]], 1);
    for (int i = t; i < NN; i += 256) {
        int hg = node_height[i];
        atomicAdd(&lc[hg], 1);
        atomicMax(&mh, hg);
    }
    __syncthreads();

    int s = 0;
    #pragma unroll
    for (int j = 0; j < 8; ++j) s += cnt[t*8 + j];
    partial[t] = s;
    __syncthreads();
    for (int off = 1; off < 256; off <<= 1) {
        int v = (t >= off) ? partial[t - off] : 0;
        __syncthreads();
        partial[t] += v;
        __syncthreads();
    }
    int run = (t == 0) ? 0 : partial[t - 1];
    int offs[8];
    #pragma unroll
    for (int j = 0; j < 8; ++j) { offs[j] = run; run += cnt[t*8 + j]; }
    __syncthreads();
    #pragma unroll
    for (int j = 0; j < 8; ++j) { int idx = t*8 + j; cnt[idx] = offs[j]; cur[idx] = offs[j]; }
    __syncthreads();

    for (int e = t; e < E; e += 256) {
        int p = parent_idx[e];
        int pos = atomicAdd(&cur[p], 1);
        ch_list[pos] = child_idx[e];
    }
    for (int i = t; i < NN; i += 256) ch_off[i] = cnt[i];
    if (t == 0) ch_off[NN] = E;

    // level bucketing
    if (t == 0) {
        int r2 = 0;
        for (int l = 0; l < NLEV; ++l) { int v = lc[l]; lev_off[l] = r2; lcur[l] = r2; r2 += v; }
        lev_off[NLEV] = r2;
        maxH[0] = mh;
    }
    __syncthreads();
    for (int i = t; i < NN; i += 256) {
        int hg = node_height[i];
        int pos = atomicAdd(&lcur[hg], 1);
        lev_nodes[pos] = i;
    }
}

// ---------------------------------------------------------------------------
// Phase 1: ix/fx/ox/ux = concat(emb,rel) @ W_* (+ b_*); 8 nodes/block.
// (proven in round 2; kept unchanged)
// ---------------------------------------------------------------------------
template<typename T>
__device__ __forceinline__ void phase1_body(
    float (*xc)[DIN],
    const int* __restrict__ xs, const int* __restrict__ rels,
    const T* __restrict__ emb_W, const T* __restrict__ rel_W,
    const T* __restrict__ W_ix, const T* __restrict__ b_ix,
    const T* __restrict__ W_fx, const T* __restrict__ b_fx,
    const T* __restrict__ W_ox, const T* __restrict__ W_ux,
    float* __restrict__ ix, float* __restrict__ fx,
    float* __restrict__ ox, float* __restrict__ ux)
{
    const int t = threadIdx.x;
    const int node0 = blockIdx.x * 8;

    #pragma unroll
    for (int j = 0; j < 8; ++j) {
        int n = node0 + j;
        if (t < DE) {
            long long w = (long long)xs[n];
            xc[j][t] = ldw(emb_W, w * DE + t);
        } else {
            long long r = (long long)rels[n];
            xc[j][t] = ldw(rel_W, r * DR + (t - DE));
        }
    }
    __syncthreads();

    float ai[8], af[8], ao[8], au[8];
    const float bi  = ldw(b_ix, t);
    const float bfv = ldw(b_fx, t);
    #pragma unroll
    for (int j = 0; j < 8; ++j) { ai[j] = bi; af[j] = bfv; ao[j] = 0.f; au[j] = 0.f; }

    for (int k = 0; k < DIN; k += 4) {
        float wi[4], wf[4], wo[4], wu[4];
        #pragma unroll
        for (int q = 0; q < 4; ++q) {
            wi[q] = ldw(W_ix, (long long)(k+q)*HH + t);
            wf[q] = ldw(W_fx, (long long)(k+q)*HH + t);
            wo[q] = ldw(W_ox, (long long)(k+q)*HH + t);
            wu[q] = ldw(W_ux, (long long)(k+q)*HH + t);
        }
        #pragma unroll
        for (int j = 0; j < 8; ++j) {
            float4 xv = *(const float4*)&xc[j][k];
            ai[j] += xv.x*wi[0] + xv.y*wi[1] + xv.z*wi[2] + xv.w*wi[3];
            af[j] += xv.x*wf[0] + xv.y*wf[1] + xv.z*wf[2] + xv.w*wf[3];
            ao[j] += xv.x*wo[0] + xv.y*wo[1] + xv.z*wo[2] + xv.w*wo[3];
            au[j] += xv.x*wu[0] + xv.y*wu[1] + xv.z*wu[2] + xv.w*wu[3];
        }
    }
    #pragma unroll
    for (int j = 0; j < 8; ++j) {
        int n = node0 + j;
        ix[n*HH + t] = ai[j];
        fx[n*HH + t] = af[j];
        ox[n*HH + t] = ao[j];
        ux[n*HH + t] = au[j];
    }
}

__global__ __launch_bounds__(256) void phase1_k(
    const int* __restrict__ flag,
    const int* __restrict__ xs, const int* __restrict__ rels,
    const void* emb_W, const void* rel_W,
    const void* W_ix, const void* b_ix,
    const void* W_fx, const void* b_fx,
    const void* W_ox, const void* W_ux,
    float* ix, float* fx, float* ox, float* ux)
{
    __shared__ float xc[8][DIN];
    if (*flag) {
        phase1_body<bf16>(xc, xs, rels, (const bf16*)emb_W, (const bf16*)rel_W,
            (const bf16*)W_ix, (const bf16*)b_ix, (const bf16*)W_fx, (const bf16*)b_fx,
            (const bf16*)W_ox, (const bf16*)W_ux, ix, fx, ox, ux);
    } else {
        phase1_body<float>(xc, xs, rels, (const float*)emb_W, (const float*)rel_W,
            (const float*)W_ix, (const float*)b_ix, (const float*)W_fx, (const float*)b_fx,
            (const float*)W_ox, (const float*)W_ux, ix, fx, ox, ux);
    }
}

// ---------------------------------------------------------------------------
// Cooperative recurrence kernel: all levels + pool in one launch.
// 256 blocks = 8 col-groups x 32 node-groups; recurrent weights LDS-resident.
// Thread map inside a block: rr = t&7 (row slot), cc = t>>3 (column 0..31).
// LDS weight layout Wl[mat][c][k], stride CPAD: weight reads are same-address
// broadcast across rr (free), banks (4c+k)%32 distinct across k (conflict-free
// within the rr-groups that differ).
// ---------------------------------------------------------------------------
template<typename T>
__device__ void coop_body(
    float* __restrict__ Wl,            // dynamic LDS: 4*WCOLS*CPAD floats
    float* __restrict__ hrow,          // [8][CPAD]
    float* __restrict__ hsum,          // [CPAD]
    float* __restrict__ fcs,           // [8][WCOLS+1]
    float* __restrict__ dgate,         // [3][WCOLS+1]
    float* __restrict__ bias,          // [2*WCOLS] : b_fh | b_ih
    int*   __restrict__ chs,           // [8]
    const int* __restrict__ lev_off, const int* __restrict__ lev_nodes,
    const int* __restrict__ maxH,
    const int* __restrict__ ch_off, const int* __restrict__ ch_list,
    const T* __restrict__ W_ih, const T* __restrict__ b_ih,
    const T* __restrict__ W_fh, const T* __restrict__ b_fh,
    const T* __restrict__ W_oh, const T* __restrict__ W_uh,
    const float* __restrict__ ix, const float* __restrict__ fx,
    const float* __restrict__ ox, const float* __restrict__ ux,
    float* __restrict__ h, float* __restrict__ c,
    const T* __restrict__ W_out, const T* __restrict__ b_out,
    void* out, int out_bf16)
{
    cg::grid_group grid = cg::this_grid();
    const int t    = threadIdx.x;
    const int bid  = blockIdx.x;
    const int cgp  = bid & 7;          // col group
    const int ng   = bid >> 3;         // node group 0..31
    const int col0 = cgp * WCOLS;
    const int rr   = t & 7;
    const int cc   = t >> 3;
    const int col  = col0 + cc;

    // ---- load recurrent weight slices into LDS (once) ----
    {
        const T* Wm[4] = { W_fh, W_ih, W_oh, W_uh };
        const int cl = t & 31, kq = t >> 5;      // kq 0..7
        for (int m = 0; m < 4; ++m) {
            float* dst = Wl + (m*WCOLS + cl)*CPAD;
            const T* src = Wm[m];
            #pragma unroll 4
            for (int kb = 0; kb < 32; ++kb) {
                int k = kb*8 + kq;
                dst[k] = ldw(src, (long long)k*HH + col0 + cl);
            }
        }
        if (t < WCOLS) {
            bias[t]         = ldw(b_fh, col0 + t);
            bias[WCOLS + t] = ldw(b_ih, col0 + t);
        }
    }
    __syncthreads();

    // ---- bottom-up levels ----
    const int mH = maxH[0];
    for (int lev = 0; lev <= mH; ++lev) {
        const int lo = lev_off[lev];
        const int nA = lev_off[lev+1] - lo;
        for (int j = ng; j < nA; j += 32) {
            const int n   = lev_nodes[lo + j];
            const int off = ch_off[n];
            const int cnt = ch_off[n+1] - off;

            hsum[t] = 0.f;               // t covers all 256 k
            float fc_acc = 0.f;
            __syncthreads();

            for (int base = 0; base < cnt; base += 8) {
                const int m = min(8, cnt - base);
                if (t < m) chs[t] = ch_list[off + base + t];
                __syncthreads();
                for (int jj = 0; jj < m; ++jj) {
                    float v = h[chs[jj]*HH + t];
                    hrow[jj*CPAD + t] = v;
                    hsum[t] += v;
                }
                __syncthreads();
                if (rr < m) {
                    const float* wf = Wl + (0*WCOLS + cc)*CPAD;
                    const float* hr = hrow + rr*CPAD;
                    float d = 0.f;
                    #pragma unroll 8
                    for (int k = 0; k < HH; k += 4) {
                        float4 w4 = *(const float4*)(wf + k);
                        float4 h4 = *(const float4*)(hr + k);
                        d += w4.x*h4.x + w4.y*h4.y + w4.z*h4.z + w4.w*h4.w;
                    }
                    float f = sigm(d + bias[cc] + fx[n*HH + col]);
                    fc_acc += f * c[chs[rr]*HH + col];
                }
                __syncthreads();         // protect hrow/chs before next batch
            }

            fcs[rr*(WCOLS+1) + cc] = fc_acc;
            if (rr < 3 && cnt > 0) {
                const float* wm = Wl + ((1+rr)*WCOLS + cc)*CPAD;
                float d = 0.f;
                #pragma unroll 8
                for (int k = 0; k < HH; k += 4) {
                    float4 w4 = *(const float4*)(wm + k);
                    float4 h4 = *(const float4*)(hsum + k);
                    d += w4.x*h4.x + w4.y*h4.y + w4.z*h4.z + w4.w*h4.w;
                }
                dgate[rr*(WCOLS+1) + cc] = d;
            }
            __syncthreads();

            if (t < WCOLS) {
                float fc = 0.f;
                #pragma unroll
                for (int r2 = 0; r2 < 8; ++r2) fc += fcs[r2*(WCOLS+1) + t];
                float di = 0.f, dof = 0.f, du = 0.f;
                if (cnt > 0) {
                    di  = dgate[0*(WCOLS+1) + t];
                    dof = dgate[1*(WCOLS+1) + t];
                    du  = dgate[2*(WCOLS+1) + t];
                }
                const int basei = n*HH + col0 + t;
                float iv = sigm(ix[basei] + di + bias[WCOLS + t]);
                float ov = sigm(ox[basei] + dof);
                float uv = tanhf(ux[basei] + du);
                float cv = iv*uv + fc;
                c[basei] = cv;
                h[basei] = ov * tanhf(cv);
            }
            __syncthreads();
        }
        grid.sync();
    }

    // ---- max-pool + output projection (blocks 0..15) ----
    if (bid < BB) {
        float* pl = hrow;                // reuse
        const int b = bid;
        float mx = -1e30f;
        for (int s = 0; s < SS; ++s) mx = fmaxf(mx, h[(b*SS + s)*HH + t]);
        pl[t] = mx;
        __syncthreads();
        if (t < LOUT) {
            float acc = ldw(b_out, (long long)t);
            for (int k = 0; k < HH; ++k) acc += pl[k] * ldw(W_out, (long long)k*LOUT + t);
            if (out_bf16) ((bf16*)out)[b*LOUT + t] = __float2bfloat16(acc);
            else          ((float*)out)[b*LOUT + t] = acc;
        }
    }
}

__global__ __launch_bounds__(256, 1) void coop_k(
    const int* flag,
    const int* lev_off, const int* lev_nodes, const int* maxH,
    const int* ch_off, const int* ch_list,
    const void* W_ih, const void* b_ih, const void* W_fh, const void* b_fh,
    const void* W_oh, const void* W_uh,
    const float* ix, const float* fx, const float* ox, const float* ux,
    float* h, float* c,
    const void* W_out, const void* b_out, void* out)
{
    extern __shared__ float Wl[];
    __shared__ float hrow[8][CPAD];
    __shared__ float hsum[CPAD];
    __shared__ float fcs[8][WCOLS+1];
    __shared__ float dgate[3][WCOLS+1];
    __shared__ float bias[2*WCOLS];
    __shared__ int   chs[8];

    if (*flag) {
        coop_body<bf16>(Wl, &hrow[0][0], hsum, &fcs[0][0], &dgate[0][0], bias, chs,
            lev_off, lev_nodes, maxH, ch_off, ch_list,
            (const bf16*)W_ih, (const bf16*)b_ih, (const bf16*)W_fh, (const bf16*)b_fh,
            (const bf16*)W_oh, (const bf16*)W_uh,
            ix, fx, ox, ux, h, c,
            (const bf16*)W_out, (const bf16*)b_out, out, 1);
    } else {
        coop_body<float>(Wl, &hrow[0][0], hsum, &fcs[0][0], &dgate[0][0], bias, chs,
            lev_off, lev_nodes, maxH, ch_off, ch_list,
            (const float*)W_ih, (const float*)b_ih, (const float*)W_fh, (const float*)b_fh,
            (const float*)W_oh, (const float*)W_uh,
            ix, fx, ox, ux, h, c,
            (const float*)W_out, (const float*)b_out, out, 0);
    }
}

// ---------------------------------------------------------------------------
extern "C" void kernel_launch(void* const* d_in, const int* in_sizes, int n_in,
                              void* d_out, int out_size, void* d_ws, size_t ws_size,
                              hipStream_t stream)
{
    const int*  xs          = (const int*)d_in[0];
    const int*  rels        = (const int*)d_in[1];
    const int*  child_idx   = (const int*)d_in[2];
    const int*  parent_idx  = (const int*)d_in[3];
    const int*  node_height = (const int*)d_in[4];
    // d_in[5] = n_levels (hardcoded NLEV)
    const void* emb_W = d_in[6];
    const void* rel_W = d_in[7];
    const void* W_ix  = d_in[8];
    const void* b_ix  = d_in[9];
    const void* W_ih  = d_in[10];
    const void* b_ih  = d_in[11];
    const void* W_fx  = d_in[12];
    const void* b_fx  = d_in[13];
    const void* W_fh  = d_in[14];
    const void* b_fh  = d_in[15];
    const void* W_ox  = d_in[16];
    const void* W_oh  = d_in[17];
    const void* W_ux  = d_in[18];
    const void* W_uh  = d_in[19];
    const void* W_out = d_in[20];
    const void* b_out = d_in[21];
    const int E = in_sizes[2];   // 2032 edges

    // workspace layout
    const size_t NH = (size_t)NN * HH;
    float* ix = (float*)d_ws;
    float* fx = ix + NH;
    float* ox = fx + NH;
    float* ux = ox + NH;
    float* h  = ux + NH;
    float* c  = h  + NH;
    int* ch_off    = (int*)(c + NH);            // NN+1
    int* ch_list   = ch_off + (NN + 4);         // E
    int* flag      = ch_list + E + 4;           // 1
    int* lev_off   = flag + 4;                  // NLEV+1
    int* lev_nodes = lev_off + (NLEV + 3);      // NN
    int* maxH      = lev_nodes + NN;            // 1

    probe_dtype<<<1, 64, 0, stream>>>((const unsigned int*)emb_W, flag);
    setup_k<<<1, 256, 0, stream>>>(child_idx, parent_idx, node_height, E,
                                   ch_off, ch_list, lev_off, lev_nodes, maxH);
    phase1_k<<<NN/8, 256, 0, stream>>>(flag, xs, rels, emb_W, rel_W,
                                       W_ix, b_ix, W_fx, b_fx, W_ox, W_ux,
                                       ix, fx, ox, ux);

    void* a_flag = (void*)flag;
    void* a_lo = (void*)lev_off;  void* a_ln = (void*)lev_nodes; void* a_mh = (void*)maxH;
    void* a_co = (void*)ch_off;   void* a_cl = (void*)ch_list;
    void* a_wih = (void*)W_ih; void* a_bih = (void*)b_ih;
    void* a_wfh = (void*)W_fh; void* a_bfh = (void*)b_fh;
    void* a_woh = (void*)W_oh; void* a_wuh = (void*)W_uh;
    void* a_ix = (void*)ix; void* a_fx = (void*)fx; void* a_ox = (void*)ox; void* a_ux = (void*)ux;
    void* a_h = (void*)h;   void* a_c = (void*)c;
    void* a_wout = (void*)W_out; void* a_bout = (void*)b_out; void* a_out = d_out;

    void* args[] = { &a_flag, &a_lo, &a_ln, &a_mh, &a_co, &a_cl,
                     &a_wih, &a_bih, &a_wfh, &a_bfh, &a_woh, &a_wuh,
                     &a_ix, &a_fx, &a_ox, &a_ux, &a_h, &a_c,
                     &a_wout, &a_bout, &a_out };
    const unsigned int shmem = 4u * WCOLS * CPAD * sizeof(float);   // 133120 B
    hipLaunchCooperativeKernel((const void*)coop_k, dim3(256), dim3(256),
                               args, shmem, stream);
}

// Round 5
// 520.195 us; speedup vs baseline: 1.9522x; 1.6712x over previous
//
#include <hip/hip_runtime.h>
#include <hip/hip_bf16.h>

// Problem constants (from reference)
#define NN   2048      // B*S nodes
#define BB   16
#define SS   128
#define HH   256       // hidden
#define DE   192
#define DR   64
#define DIN  256
#define LOUT 12
#define NLEV 21

#define NT   16        // trees
#define CB   16        // col-blocks per tree
#define WC   16        // columns per block
#define RB   16        // row slots (256 threads = RB x WC)
#define CPAD 260       // padded row stride (float4-aligned)

__device__ __forceinline__ float sigm(float x){ return 1.f/(1.f + __expf(-x)); }

// ---------------------------------------------------------------------------
// Setup (1 block): CSR children adjacency, per-(tree,height) sorted node list,
// zero ready/pool counters.
// ---------------------------------------------------------------------------
__global__ __launch_bounds__(256) void setup_k(
    const int* __restrict__ child_idx, const int* __restrict__ parent_idx,
    const int* __restrict__ node_height, int E,
    int* __restrict__ ch_off, int* __restrict__ ch_list,
    int* __restrict__ tn, int* __restrict__ tlo,
    int* __restrict__ ready, int* __restrict__ poolctr)
{
    __shared__ int cnt[NN];
    __shared__ int cur[NN];
    __shared__ int partial[256];
    __shared__ int tl[NT*NLEV];
    __shared__ int tcur[NT*NLEV];
    const int t = threadIdx.x;

    for (int i = t; i < NN; i += 256) { cnt[i] = 0; ready[i] = 0; }
    for (int i = t; i < NT*NLEV; i += 256) tl[i] = 0;
    if (t < NT) poolctr[t] = 0;
    __syncthreads();
    for (int e = t; e < E; e += 256) atomicAdd(&cnt[parent_idx[e]], 1);
    for (int i = t; i < NN; i += 256) {
        int b = i >> 7, hg = node_height[i];
        atomicAdd(&tl[b*NLEV + hg], 1);
    }
    __syncthreads();

    // CSR prefix over 2048 counters
    int s = 0;
    #pragma unroll
    for (int j = 0; j < 8; ++j) s += cnt[t*8 + j];
    partial[t] = s;
    __syncthreads();
    for (int off = 1; off < 256; off <<= 1) {
        int v = (t >= off) ? partial[t - off] : 0;
        __syncthreads();
        partial[t] += v;
        __syncthreads();
    }
    int run = (t == 0) ? 0 : partial[t - 1];
    int offs[8];
    #pragma unroll
    for (int j = 0; j < 8; ++j) { offs[j] = run; run += cnt[t*8 + j]; }
    __syncthreads();
    #pragma unroll
    for (int j = 0; j < 8; ++j) { int idx = t*8 + j; cnt[idx] = offs[j]; cur[idx] = offs[j]; }
    __syncthreads();
    for (int e = t; e < E; e += 256) {
        int p = parent_idx[e];
        int pos = atomicAdd(&cur[p], 1);
        ch_list[pos] = child_idx[e];
    }
    for (int i = t; i < NN; i += 256) ch_off[i] = cnt[i];
    if (t == 0) ch_off[NN] = E;

    // per-tree level offsets into tn (tree b owns tn[b*128 .. b*128+128))
    if (t < NT) {
        int r = t * 128;
        for (int l = 0; l < NLEV; ++l) {
            int v = tl[t*NLEV + l];
            tlo[t*(NLEV+1) + l] = r;
            tcur[t*NLEV + l] = r;
            r += v;
        }
        tlo[t*(NLEV+1) + NLEV] = r;
    }
    __syncthreads();
    for (int i = t; i < NN; i += 256) {
        int b = i >> 7, hg = node_height[i];
        int pos = atomicAdd(&tcur[b*NLEV + hg], 1);
        tn[pos] = i;
    }
}

// ---------------------------------------------------------------------------
// Phase 1: ix/fx/ox/ux = concat(emb,rel) @ W_* (+ b_*); 8 nodes/block. FP32.
// ---------------------------------------------------------------------------
__global__ __launch_bounds__(256) void phase1_k(
    const int* __restrict__ xs, const int* __restrict__ rels,
    const float* __restrict__ emb_W, const float* __restrict__ rel_W,
    const float* __restrict__ W_ix, const float* __restrict__ b_ix,
    const float* __restrict__ W_fx, const float* __restrict__ b_fx,
    const float* __restrict__ W_ox, const float* __restrict__ W_ux,
    float* __restrict__ ix, float* __restrict__ fx,
    float* __restrict__ ox, float* __restrict__ ux)
{
    const int t = threadIdx.x;
    const int node0 = blockIdx.x * 8;
    __shared__ float xc[8][DIN];

    #pragma unroll
    for (int j = 0; j < 8; ++j) {
        int n = node0 + j;
        if (t < DE) {
            long long w = (long long)xs[n];
            xc[j][t] = emb_W[w * DE + t];
        } else {
            long long r = (long long)rels[n];
            xc[j][t] = rel_W[r * DR + (t - DE)];
        }
    }
    __syncthreads();

    float ai[8], af[8], ao[8], au[8];
    const float bi  = b_ix[t];
    const float bfv = b_fx[t];
    #pragma unroll
    for (int j = 0; j < 8; ++j) { ai[j] = bi; af[j] = bfv; ao[j] = 0.f; au[j] = 0.f; }

    for (int k = 0; k < DIN; k += 4) {
        float wi[4], wf[4], wo[4], wu[4];
        #pragma unroll
        for (int q = 0; q < 4; ++q) {
            wi[q] = W_ix[(k+q)*HH + t];
            wf[q] = W_fx[(k+q)*HH + t];
            wo[q] = W_ox[(k+q)*HH + t];
            wu[q] = W_ux[(k+q)*HH + t];
        }
        #pragma unroll
        for (int j = 0; j < 8; ++j) {
            float4 xv = *(const float4*)&xc[j][k];
            ai[j] += xv.x*wi[0] + xv.y*wi[1] + xv.z*wi[2] + xv.w*wi[3];
            af[j] += xv.x*wf[0] + xv.y*wf[1] + xv.z*wf[2] + xv.w*wf[3];
            ao[j] += xv.x*wo[0] + xv.y*wo[1] + xv.z*wo[2] + xv.w*wo[3];
            au[j] += xv.x*wu[0] + xv.y*wu[1] + xv.z*wu[2] + xv.w*wu[3];
        }
    }
    #pragma unroll
    for (int j = 0; j < 8; ++j) {
        int n = node0 + j;
        ix[n*HH + t] = ai[j];
        fx[n*HH + t] = af[j];
        ox[n*HH + t] = ao[j];
        ux[n*HH + t] = au[j];
    }
}

// ---------------------------------------------------------------------------
// Dataflow recurrence kernel: 256 blocks = 16 trees x 16 col-blocks.
// No grid barriers; per-node ready counters (release/acquire via fences).
// Recurrent weight slices (4 mats x 16 cols x 256 k, fp32) LDS-resident.
// Thread map: cc = t&15 (column), rr = t>>4 (row slot 0..15).
// ---------------------------------------------------------------------------
__global__ __launch_bounds__(256, 1) void tree_k(
    const int* tn, const int* tlo, const int* ch_off, const int* ch_list,
    const float* W_ih, const float* b_ih,
    const float* W_fh, const float* b_fh,
    const float* W_oh, const float* W_uh,
    const float* ix, const float* fx, const float* ox, const float* ux,
    float* h, float* c, int* ready,
    float* poolbuf, int* poolctr,
    const float* W_out, const float* b_out, float* out)
{
    extern __shared__ float Wl[];           // [4][WC][CPAD]
    __shared__ float hrow[RB][CPAD];
    __shared__ float hsN[RB][CPAD];
    __shared__ float part[3*RB][WC+1];
    __shared__ float fcN[RB][WC+1];
    __shared__ float fxv[RB][WC+1];
    __shared__ float crow[RB][WC+1];
    __shared__ float biasF[WC], biasI[WC];
    __shared__ int   chs[RB], slts[RB];
    __shared__ int   csum[RB+1];
    __shared__ int   nodes_s[RB];

    const int t    = threadIdx.x;
    const int bid  = blockIdx.x;
    const int b    = bid >> 4;           // tree
    const int cgp  = bid & 15;           // col group
    const int col0 = cgp * WC;
    const int cc   = t & 15;
    const int rr   = t >> 4;             // 0..15

    // ---- load recurrent weight slices into LDS (fh, ih, oh, uh) ----
    {
        const float* Wm[4] = { W_fh, W_ih, W_oh, W_uh };
        for (int m = 0; m < 4; ++m) {
            float* dst = Wl + (m*WC + cc)*CPAD;
            const float* src = Wm[m] + col0 + cc;
            #pragma unroll 4
            for (int kb = 0; kb < 16; ++kb) {
                int k = kb*16 + rr;
                dst[k] = src[(long long)k*HH];
            }
        }
        if (t < WC) { biasF[t] = b_fh[col0+t]; biasI[t] = b_ih[col0+t]; }
    }
    __syncthreads();

    // ---- bottom-up dataflow over this tree's nodes (height-sorted) ----
    const int tbase = b * (NLEV+1);
    for (int lev = 0; lev < NLEV; ++lev) {
        const int s0 = tlo[tbase + lev];
        const int s1 = tlo[tbase + lev + 1];
        for (int cs = s0; cs < s1; cs += RB) {
            const int nbN = min(RB, s1 - cs);
            if (t < nbN) nodes_s[t] = tn[cs + t];
            __syncthreads();

            if (lev == 0) {
                // ---- leaf chunk: gates are elementwise on ix/ox/ux ----
                if (rr < nbN) {
                    int base = nodes_s[rr]*HH + col0 + cc;
                    float iv = sigm(ix[base] + biasI[cc]);
                    float ov = sigm(ox[base]);
                    float uv = tanhf(ux[base]);
                    float cv = iv * uv;
                    c[base] = cv;
                    h[base] = ov * tanhf(cv);
                }
                __syncthreads();
                if (t < nbN) { __threadfence(); atomicAdd(&ready[nodes_s[t]], 1); }
                __syncthreads();
                continue;
            }

            // ---- internal chunk ----
            if (t < nbN) csum[t+1] = ch_off[nodes_s[t]+1] - ch_off[nodes_s[t]];
            if (t == 0)  csum[0] = 0;
            __syncthreads();

            if (t == 0) {
                for (int s2 = 1; s2 <= nbN; ++s2) csum[s2] += csum[s2-1];
                // spin until all children of all chunk nodes are complete
                for (int s2 = 0; s2 < nbN; ++s2) {
                    int n = nodes_s[s2];
                    int e1 = ch_off[n+1];
                    for (int e = ch_off[n]; e < e1; ++e) {
                        int chn = ch_list[e];
                        while (__hip_atomic_load(&ready[chn], __ATOMIC_RELAXED,
                                                 __HIP_MEMORY_SCOPE_AGENT) < CB)
                            __builtin_amdgcn_s_sleep(1);
                    }
                }
                __threadfence();   // acquire
            }
            for (int r2 = 0; r2 < nbN; ++r2) hsN[r2][t] = 0.f;
            fcN[rr][cc] = 0.f;
            if (rr < nbN) fxv[rr][cc] = fx[nodes_s[rr]*HH + col0 + cc];
            __syncthreads();

            const int Ech = csum[nbN];
            for (int eb = 0; eb < Ech; eb += RB) {
                const int m = min(RB, Ech - eb);
                if (t < m) {
                    int e = eb + t;
                    int s2 = 0;
                    while (csum[s2+1] <= e) ++s2;
                    int n = nodes_s[s2];
                    chs[t]  = ch_list[ch_off[n] + (e - csum[s2])];
                    slts[t] = s2;
                }
                __syncthreads();
                // stage child h rows (vectorized, coalesced)
                if (rr < m) {
                    const float* src = h + (long long)chs[rr]*HH + cc*16;
                    float* dst = &hrow[rr][cc*16];
                    #pragma unroll
                    for (int q = 0; q < 4; ++q)
                        *(float4*)(dst + q*4) = *(const float4*)(src + q*4);
                    crow[rr][cc] = c[(long long)chs[rr]*HH + col0 + cc];
                }
                __syncthreads();
                // hsum accumulate (column-private, race-free)
                for (int jj = 0; jj < m; ++jj)
                    hsN[slts[jj]][t] += hrow[jj][t];
                // f-gate dots, depth-adaptive split
                const int nb = (m<=1)?1:(m<=2)?2:(m<=4)?4:(m<=8)?8:16;
                {
                    int slot = rr % nb;
                    int ksl  = rr / nb;
                    float d = 0.f;
                    if (slot < m) {
                        const float* wf = Wl + (0*WC + cc)*CPAD;
                        const float* hr = hrow[slot];
                        int k0 = ksl * (16*nb), k1 = k0 + 16*nb;
                        for (int k = k0; k < k1; k += 4) {
                            float4 w4 = *(const float4*)(wf + k);
                            float4 h4 = *(const float4*)(hr + k);
                            d += w4.x*h4.x + w4.y*h4.y + w4.z*h4.z + w4.w*h4.w;
                        }
                    }
                    part[rr][cc] = d;
                }
                __syncthreads();
                if (rr < m) {
                    float d = 0.f;
                    for (int j = rr; j < RB; j += nb) d += part[j][cc];
                    float f = sigm(d + biasF[cc] + fxv[slts[rr]][cc]);
                    atomicAdd(&fcN[slts[rr]][cc], f * crow[rr][cc]);
                }
                __syncthreads();
            }

            // i/o/u dots over hsum, depth-adaptive
            {
                const int nb2 = (nbN<=1)?1:(nbN<=2)?2:(nbN<=4)?4:(nbN<=8)?8:16;
                int slot = rr % nb2;
                int ksl  = rr / nb2;
                int k0 = ksl * (16*nb2), k1 = k0 + 16*nb2;
                for (int mat = 0; mat < 3; ++mat) {
                    float d = 0.f;
                    if (slot < nbN) {
                        const float* wm = Wl + ((1+mat)*WC + cc)*CPAD;
                        const float* hr = hsN[slot];
                        for (int k = k0; k < k1; k += 4) {
                            float4 w4 = *(const float4*)(wm + k);
                            float4 h4 = *(const float4*)(hr + k);
                            d += w4.x*h4.x + w4.y*h4.y + w4.z*h4.z + w4.w*h4.w;
                        }
                    }
                    part[mat*RB + rr][cc] = d;
                }
                __syncthreads();
                if (rr < nbN) {
                    float di = 0.f, dof = 0.f, du = 0.f;
                    for (int j = rr; j < RB; j += nb2) {
                        di  += part[0*RB + j][cc];
                        dof += part[1*RB + j][cc];
                        du  += part[2*RB + j][cc];
                    }
                    int base = nodes_s[rr]*HH + col0 + cc;
                    float iv = sigm(ix[base] + di + biasI[cc]);
                    float ov = sigm(ox[base] + dof);
                    float uv = tanhf(ux[base] + du);
                    float cv = iv*uv + fcN[rr][cc];
                    c[base] = cv;
                    h[base] = ov * tanhf(cv);
                }
                __syncthreads();
                if (t < nbN) { __threadfence(); atomicAdd(&ready[nodes_s[t]], 1); }
                __syncthreads();
            }
        }
    }

    // ---- max-pool own columns, then tree's cgp==0 block emits output ----
    {
        float mx = -3.4e38f;
        for (int s2 = rr; s2 < SS; s2 += RB)
            mx = fmaxf(mx, h[(b*SS + s2)*HH + col0 + cc]);
        part[rr][cc] = mx;
        __syncthreads();
        if (t < WC) {
            float m2 = part[0][t];
            #pragma unroll
            for (int r2 = 1; r2 < RB; ++r2) m2 = fmaxf(m2, part[r2][t]);
            poolbuf[b*HH + col0 + t] = m2;
        }
        __syncthreads();
        if (t == 0) { __threadfence(); atomicAdd(&poolctr[b], 1); }
    }
    if (cgp == 0) {
        if (t == 0) {
            while (__hip_atomic_load(&poolctr[b], __ATOMIC_RELAXED,
                                     __HIP_MEMORY_SCOPE_AGENT) < CB)
                __builtin_amdgcn_s_sleep(1);
            __threadfence();
        }
        __syncthreads();
        if (t < LOUT) {
            float acc = b_out[t];
            for (int k = 0; k < HH; ++k)
                acc += poolbuf[b*HH + k] * W_out[k*LOUT + t];
            out[b*LOUT + t] = acc;
        }
    }
}

// ---------------------------------------------------------------------------
extern "C" void kernel_launch(void* const* d_in, const int* in_sizes, int n_in,
                              void* d_out, int out_size, void* d_ws, size_t ws_size,
                              hipStream_t stream)
{
    const int* xs          = (const int*)d_in[0];
    const int* rels        = (const int*)d_in[1];
    const int* child_idx   = (const int*)d_in[2];
    const int* parent_idx  = (const int*)d_in[3];
    const int* node_height = (const int*)d_in[4];
    // d_in[5] = n_levels (hardcoded NLEV)
    const float* emb_W = (const float*)d_in[6];
    const float* rel_W = (const float*)d_in[7];
    const float* W_ix  = (const float*)d_in[8];
    const float* b_ix  = (const float*)d_in[9];
    const float* W_ih  = (const float*)d_in[10];
    const float* b_ih  = (const float*)d_in[11];
    const float* W_fx  = (const float*)d_in[12];
    const float* b_fx  = (const float*)d_in[13];
    const float* W_fh  = (const float*)d_in[14];
    const float* b_fh  = (const float*)d_in[15];
    const float* W_ox  = (const float*)d_in[16];
    const float* W_oh  = (const float*)d_in[17];
    const float* W_ux  = (const float*)d_in[18];
    const float* W_uh  = (const float*)d_in[19];
    const float* W_out = (const float*)d_in[20];
    const float* b_out = (const float*)d_in[21];
    const int E = in_sizes[2];   // 2032 edges

    const size_t NH = (size_t)NN * HH;
    float* ix = (float*)d_ws;
    float* fx = ix + NH;
    float* ox = fx + NH;
    float* ux = ox + NH;
    float* h  = ux + NH;
    float* c  = h  + NH;
    float* poolbuf = c + NH;                    // 16*256 floats
    int* ch_off  = (int*)(poolbuf + BB*HH);     // NN+1
    int* ch_list = ch_off + (NN + 4);           // E
    int* tn      = ch_list + E + 4;             // NN
    int* tlo     = tn + NN;                     // NT*(NLEV+1)
    int* ready   = tlo + NT*(NLEV+1) + 4;       // NN
    int* poolctr = ready + NN;                  // NT

    setup_k<<<1, 256, 0, stream>>>(child_idx, parent_idx, node_height, E,
                                   ch_off, ch_list, tn, tlo, ready, poolctr);
    phase1_k<<<NN/8, 256, 0, stream>>>(xs, rels, emb_W, rel_W,
                                       W_ix, b_ix, W_fx, b_fx, W_ox, W_ux,
                                       ix, fx, ox, ux);

    void* a_tn = (void*)tn;   void* a_tlo = (void*)tlo;
    void* a_co = (void*)ch_off; void* a_cl = (void*)ch_list;
    void* a_wih = (void*)W_ih; void* a_bih = (void*)b_ih;
    void* a_wfh = (void*)W_fh; void* a_bfh = (void*)b_fh;
    void* a_woh = (void*)W_oh; void* a_wuh = (void*)W_uh;
    void* a_ix = (void*)ix; void* a_fx = (void*)fx; void* a_ox = (void*)ox; void* a_ux = (void*)ux;
    void* a_h = (void*)h; void* a_c = (void*)c; void* a_rd = (void*)ready;
    void* a_pb = (void*)poolbuf; void* a_pc = (void*)poolctr;
    void* a_wout = (void*)W_out; void* a_bout = (void*)b_out; void* a_out = d_out;

    void* args[] = { &a_tn, &a_tlo, &a_co, &a_cl,
                     &a_wih, &a_bih, &a_wfh, &a_bfh, &a_woh, &a_wuh,
                     &a_ix, &a_fx, &a_ox, &a_ux, &a_h, &a_c, &a_rd,
                     &a_pb, &a_pc, &a_wout, &a_bout, &a_out };
    const unsigned int shmem = 4u * WC * CPAD * sizeof(float);   // 66560 B
    hipLaunchCooperativeKernel((const void*)tree_k, dim3(NT*CB), dim3(256),
                               args, shmem, stream);
}

// Round 6
// 461.590 us; speedup vs baseline: 2.2001x; 1.1270x over previous
//
#include <hip/hip_runtime.h>
#include <hip/hip_bf16.h>

// Problem constants (from reference)
#define NN   2048      // B*S nodes
#define BB   16
#define SS   128
#define HH   256       // hidden
#define DE   192
#define DR   64
#define DIN  256
#define LOUT 12
#define NLEV 21
#define TE   127       // edges per tree (S-1), contiguous slice per tree

#define NT   16        // trees
#define CB   16        // col-blocks per tree
#define WC   16        // columns per block
#define RB   16        // row slots (256 threads = RB x WC)
#define CPAD 260       // padded row stride (float4-aligned)

__device__ __forceinline__ float sigm(float x){ return 1.f/(1.f + __expf(-x)); }

// ---------------------------------------------------------------------------
// Phase 1: ix/fx/ox/ux = concat(emb,rel) @ W_* (+ b_*); 8 nodes/block. FP32.
// ---------------------------------------------------------------------------
__global__ __launch_bounds__(256) void phase1_k(
    const int* __restrict__ xs, const int* __restrict__ rels,
    const float* __restrict__ emb_W, const float* __restrict__ rel_W,
    const float* __restrict__ W_ix, const float* __restrict__ b_ix,
    const float* __restrict__ W_fx, const float* __restrict__ b_fx,
    const float* __restrict__ W_ox, const float* __restrict__ W_ux,
    float* __restrict__ ix, float* __restrict__ fx,
    float* __restrict__ ox, float* __restrict__ ux)
{
    const int t = threadIdx.x;
    const int node0 = blockIdx.x * 8;
    __shared__ float xc[8][DIN];

    #pragma unroll
    for (int j = 0; j < 8; ++j) {
        int n = node0 + j;
        if (t < DE) {
            long long w = (long long)xs[n];
            xc[j][t] = emb_W[w * DE + t];
        } else {
            long long r = (long long)rels[n];
            xc[j][t] = rel_W[r * DR + (t - DE)];
        }
    }
    __syncthreads();

    float ai[8], af[8], ao[8], au[8];
    const float bi  = b_ix[t];
    const float bfv = b_fx[t];
    #pragma unroll
    for (int j = 0; j < 8; ++j) { ai[j] = bi; af[j] = bfv; ao[j] = 0.f; au[j] = 0.f; }

    for (int k = 0; k < DIN; k += 4) {
        float wi[4], wf[4], wo[4], wu[4];
        #pragma unroll
        for (int q = 0; q < 4; ++q) {
            wi[q] = W_ix[(k+q)*HH + t];
            wf[q] = W_fx[(k+q)*HH + t];
            wo[q] = W_ox[(k+q)*HH + t];
            wu[q] = W_ux[(k+q)*HH + t];
        }
        #pragma unroll
        for (int j = 0; j < 8; ++j) {
            float4 xv = *(const float4*)&xc[j][k];
            ai[j] += xv.x*wi[0] + xv.y*wi[1] + xv.z*wi[2] + xv.w*wi[3];
            af[j] += xv.x*wf[0] + xv.y*wf[1] + xv.z*wf[2] + xv.w*wf[3];
            ao[j] += xv.x*wo[0] + xv.y*wo[1] + xv.z*wo[2] + xv.w*wo[3];
            au[j] += xv.x*wu[0] + xv.y*wu[1] + xv.z*wu[2] + xv.w*wu[3];
        }
    }
    #pragma unroll
    for (int j = 0; j < 8; ++j) {
        int n = node0 + j;
        ix[n*HH + t] = ai[j];
        fx[n*HH + t] = af[j];
        ox[n*HH + t] = ao[j];
        ux[n*HH + t] = au[j];
    }
}

// ---------------------------------------------------------------------------
// Dataflow recurrence kernel: 256 blocks = 16 trees x 16 col-blocks.
// Per-(tree,level) counters; proj slices + c + CSR all LDS-resident so
// acquire-fence cache invalidations only cost re-fetch of children h.
// XCD-affine mapping: all 16 blocks of a tree on one XCD (bid%8 heuristic).
// Thread map: cc = t&15 (column), rr = t>>4 (row slot 0..15).
// ---------------------------------------------------------------------------
__global__ __launch_bounds__(256, 1) void tree_k(
    const int* __restrict__ child_idx, const int* __restrict__ parent_idx,
    const int* __restrict__ node_height,
    const float* __restrict__ W_ih, const float* __restrict__ b_ih,
    const float* __restrict__ W_fh, const float* __restrict__ b_fh,
    const float* __restrict__ W_oh, const float* __restrict__ W_uh,
    const float* __restrict__ ix, const float* __restrict__ fx,
    const float* __restrict__ ox, const float* __restrict__ ux,
    float* __restrict__ h, int* __restrict__ levctr,
    float* __restrict__ poolbuf, int* __restrict__ poolctr,
    const float* __restrict__ W_out, const float* __restrict__ b_out,
    float* __restrict__ out)
{
    extern __shared__ float Wl[];            // [4][WC][CPAD] recurrent weights
    __shared__ float projL[4][SS][WC];       // ix,fx,ox,ux own-col slices
    __shared__ float cloc[SS][WC+1];         // cell state, never global
    __shared__ float hstage[RB][CPAD];
    __shared__ float hsN[RB][CPAD];
    __shared__ float part[3*RB][WC+1];
    __shared__ float fcN[RB][WC+1];
    __shared__ float biasF[WC], biasI[WC];
    __shared__ int loff[SS+1], lcur[SS], llist[SS];
    __shared__ int lvoff[NLEV+1], lvcur[NLEV], lvnodes[SS];
    __shared__ int chs[RB], slts[RB], csum[RB+1], nodes_s[RB];
    __shared__ int s_maxH;

    const int t   = threadIdx.x;
    const int bid = blockIdx.x;
    // XCD-affine: tree b's 16 blocks all have bid % 8 == b % 8
    const int xcd  = bid & 7;
    const int idx  = bid >> 3;               // 0..31
    const int b    = xcd + 8 * (idx >> 4);   // tree
    const int cgp  = idx & 15;               // col group
    const int col0 = cgp * WC;
    const int cc   = t & 15;
    const int rr   = t >> 4;                 // 0..15

    // ---- build this tree's CSR + level lists in LDS (local node ids) ----
    if (t < SS)   lcur[t]  = 0;
    if (t < NLEV) lvcur[t] = 0;
    if (t == 0)   s_maxH   = 0;
    __syncthreads();
    if (t < TE) { int p = parent_idx[b*TE + t] - b*SS; atomicAdd(&lcur[p], 1); }
    if (t < SS) { int hg = node_height[b*SS + t]; atomicAdd(&lvcur[hg], 1); atomicMax(&s_maxH, hg); }
    __syncthreads();
    if (t == 0) {
        int off = 0;
        for (int i = 0; i < SS; ++i) { int v = lcur[i]; loff[i] = off; lcur[i] = off; off += v; }
        loff[SS] = off;
        off = 0;
        for (int l = 0; l < NLEV; ++l) { int v = lvcur[l]; lvoff[l] = off; lvcur[l] = off; off += v; }
        lvoff[NLEV] = off;
    }
    __syncthreads();
    if (t < TE) {
        int e = b*TE + t;
        int p = parent_idx[e] - b*SS;
        int pos = atomicAdd(&lcur[p], 1);
        llist[pos] = child_idx[e] - b*SS;
    }
    if (t < SS) {
        int hg = node_height[b*SS + t];
        int pos = atomicAdd(&lvcur[hg], 1);
        lvnodes[pos] = t;
    }

    // ---- load recurrent weight slices into LDS (fh, ih, oh, uh) ----
    {
        const float* Wm[4] = { W_fh, W_ih, W_oh, W_uh };
        for (int m = 0; m < 4; ++m) {
            float* dst = Wl + (m*WC + cc)*CPAD;
            const float* src = Wm[m] + col0 + cc;
            #pragma unroll 4
            for (int kb = 0; kb < 16; ++kb) {
                int k = kb*16 + rr;
                dst[k] = src[(long long)k*HH];
            }
        }
        if (t < WC) { biasF[t] = b_fh[col0+t]; biasI[t] = b_ih[col0+t]; }
    }

    // ---- preload proj slices into LDS (fence-immune) ----
    {
        const float* P[4] = { ix, fx, ox, ux };
        for (int m = 0; m < 4; ++m) {
            #pragma unroll
            for (int base = 0; base < 512; base += 256) {
                int i = base + t;                 // float4 index
                int n = i >> 2, q = i & 3;
                *(float4*)&projL[m][n][q*4] =
                    *(const float4*)&P[m][(long long)(b*SS + n)*HH + col0 + q*4];
            }
        }
    }
    __syncthreads();

    // ---- level 0: leaves (elementwise gates) ----
    {
        const int s0 = lvoff[0], s1 = lvoff[1];
        for (int cs = s0; cs < s1; cs += RB) {
            const int nbN = min(RB, s1 - cs);
            if (rr < nbN) {
                int n = lvnodes[cs + rr];
                float iv = sigm(projL[0][n][cc] + biasI[cc]);
                float ov = sigm(projL[2][n][cc]);
                float uv = tanhf(projL[3][n][cc]);
                float cv = iv * uv;
                cloc[n][cc] = cv;
                h[(long long)(b*SS + n)*HH + col0 + cc] = ov * tanhf(cv);
            }
        }
        __syncthreads();                         // drains each wave's vmem
        if (t == 0) { __threadfence(); atomicAdd(&levctr[b*32 + 0], 1); }
    }

    // ---- levels 1..maxH ----
    const int mH = s_maxH;
    for (int lev = 1; lev <= mH; ++lev) {
        if (t == 0) {
            while (__hip_atomic_load(&levctr[b*32 + lev - 1], __ATOMIC_RELAXED,
                                     __HIP_MEMORY_SCOPE_AGENT) < CB)
                __builtin_amdgcn_s_sleep(1);
            __threadfence();                     // acquire
        }
        __syncthreads();

        const int s0 = lvoff[lev], s1 = lvoff[lev+1];
        for (int cs = s0; cs < s1; cs += RB) {
            const int nbN = min(RB, s1 - cs);
            if (t < nbN) {
                int n = lvnodes[cs + t];
                nodes_s[t] = n;
                csum[t+1]  = loff[n+1] - loff[n];
            }
            if (t == 0) csum[0] = 0;
            __syncthreads();
            if (t == 0) for (int i = 1; i <= nbN; ++i) csum[i] += csum[i-1];
            for (int r2 = 0; r2 < nbN; ++r2) hsN[r2][t] = 0.f;
            fcN[rr][cc] = 0.f;
            __syncthreads();

            const int Ech = csum[nbN];
            for (int eb = 0; eb < Ech; eb += RB) {
                const int m = min(RB, Ech - eb);
                if (t < m) {
                    int e = eb + t;
                    int s2 = 0;
                    while (csum[s2+1] <= e) ++s2;
                    chs[t]  = llist[loff[nodes_s[s2]] + (e - csum[s2])];
                    slts[t] = s2;
                }
                __syncthreads();
                if (rr < m) {
                    const float* src = h + (long long)(b*SS + chs[rr])*HH + cc*16;
                    float* dst = &hstage[rr][cc*16];
                    #pragma unroll
                    for (int q = 0; q < 4; ++q)
                        *(float4*)(dst + q*4) = *(const float4*)(src + q*4);
                }
                __syncthreads();
                for (int jj = 0; jj < m; ++jj)
                    hsN[slts[jj]][t] += hstage[jj][t];
                const int nb = (m<=1)?1:(m<=2)?2:(m<=4)?4:(m<=8)?8:16;
                {
                    int slot = rr % nb;
                    int ksl  = rr / nb;
                    float d = 0.f;
                    if (slot < m) {
                        const float* wf = Wl + (0*WC + cc)*CPAD;
                        const float* hr = hstage[slot];
                        int k0 = ksl * (16*nb), k1 = k0 + 16*nb;
                        for (int k = k0; k < k1; k += 4) {
                            float4 w4 = *(const float4*)(wf + k);
                            float4 h4 = *(const float4*)(hr + k);
                            d += w4.x*h4.x + w4.y*h4.y + w4.z*h4.z + w4.w*h4.w;
                        }
                    }
                    part[rr][cc] = d;
                }
                __syncthreads();
                if (rr < m) {
                    float d = 0.f;
                    for (int j = rr; j < RB; j += nb) d += part[j][cc];
                    float f = sigm(d + biasF[cc] + projL[1][nodes_s[slts[rr]]][cc]);
                    atomicAdd(&fcN[slts[rr]][cc], f * cloc[chs[rr]][cc]);
                }
                __syncthreads();
            }

            // i/o/u dots over hsum, depth-adaptive
            {
                const int nb2 = (nbN<=1)?1:(nbN<=2)?2:(nbN<=4)?4:(nbN<=8)?8:16;
                int slot = rr % nb2;
                int ksl  = rr / nb2;
                int k0 = ksl * (16*nb2), k1 = k0 + 16*nb2;
                for (int mat = 0; mat < 3; ++mat) {
                    float d = 0.f;
                    if (slot < nbN) {
                        const float* wm = Wl + ((1+mat)*WC + cc)*CPAD;
                        const float* hr = hsN[slot];
                        for (int k = k0; k < k1; k += 4) {
                            float4 w4 = *(const float4*)(wm + k);
                            float4 h4 = *(const float4*)(hr + k);
                            d += w4.x*h4.x + w4.y*h4.y + w4.z*h4.z + w4.w*h4.w;
                        }
                    }
                    part[mat*RB + rr][cc] = d;
                }
                __syncthreads();
                if (rr < nbN) {
                    float di = 0.f, dof = 0.f, du = 0.f;
                    for (int j = rr; j < RB; j += nb2) {
                        di  += part[0*RB + j][cc];
                        dof += part[1*RB + j][cc];
                        du  += part[2*RB + j][cc];
                    }
                    int n = nodes_s[rr];
                    float iv = sigm(projL[0][n][cc] + di + biasI[cc]);
                    float ov = sigm(projL[2][n][cc] + dof);
                    float uv = tanhf(projL[3][n][cc] + du);
                    float cv = iv*uv + fcN[rr][cc];
                    cloc[n][cc] = cv;
                    h[(long long)(b*SS + n)*HH + col0 + cc] = ov * tanhf(cv);
                }
                __syncthreads();
            }
        }
        if (t == 0) { __threadfence(); atomicAdd(&levctr[b*32 + lev], 1); }
    }

    // ---- max-pool own columns (self-written h), then cgp==0 emits output ----
    {
        float mx = -3.4e38f;
        for (int s2 = rr; s2 < SS; s2 += RB)
            mx = fmaxf(mx, h[(long long)(b*SS + s2)*HH + col0 + cc]);
        part[rr][cc] = mx;
        __syncthreads();
        if (t < WC) {
            float m2 = part[0][t];
            #pragma unroll
            for (int r2 = 1; r2 < RB; ++r2) m2 = fmaxf(m2, part[r2][t]);
            poolbuf[b*HH + col0 + t] = m2;
        }
        __syncthreads();
        if (t == 0) { __threadfence(); atomicAdd(&poolctr[b], 1); }
    }
    if (cgp == 0) {
        if (t == 0) {
            while (__hip_atomic_load(&poolctr[b], __ATOMIC_RELAXED,
                                     __HIP_MEMORY_SCOPE_AGENT) < CB)
                __builtin_amdgcn_s_sleep(1);
            __threadfence();
        }
        __syncthreads();
        if (t < LOUT) {
            float acc = b_out[t];
            for (int k = 0; k < HH; ++k)
                acc += poolbuf[b*HH + k] * W_out[k*LOUT + t];
            out[b*LOUT + t] = acc;
        }
    }
}

// ---------------------------------------------------------------------------
extern "C" void kernel_launch(void* const* d_in, const int* in_sizes, int n_in,
                              void* d_out, int out_size, void* d_ws, size_t ws_size,
                              hipStream_t stream)
{
    const int* xs          = (const int*)d_in[0];
    const int* rels        = (const int*)d_in[1];
    const int* child_idx   = (const int*)d_in[2];
    const int* parent_idx  = (const int*)d_in[3];
    const int* node_height = (const int*)d_in[4];
    // d_in[5] = n_levels (hardcoded NLEV)
    const float* emb_W = (const float*)d_in[6];
    const float* rel_W = (const float*)d_in[7];
    const float* W_ix  = (const float*)d_in[8];
    const float* b_ix  = (const float*)d_in[9];
    const float* W_ih  = (const float*)d_in[10];
    const float* b_ih  = (const float*)d_in[11];
    const float* W_fx  = (const float*)d_in[12];
    const float* b_fx  = (const float*)d_in[13];
    const float* W_fh  = (const float*)d_in[14];
    const float* b_fh  = (const float*)d_in[15];
    const float* W_ox  = (const float*)d_in[16];
    const float* W_oh  = (const float*)d_in[17];
    const float* W_ux  = (const float*)d_in[18];
    const float* W_uh  = (const float*)d_in[19];
    const float* W_out = (const float*)d_in[20];
    const float* b_out = (const float*)d_in[21];

    const size_t NH = (size_t)NN * HH;
    float* ix = (float*)d_ws;
    float* fx = ix + NH;
    float* ox = fx + NH;
    float* ux = ox + NH;
    float* h  = ux + NH;
    float* poolbuf = h + NH;                    // BB*HH floats
    int* levctr  = (int*)(poolbuf + BB*HH);     // NT*32
    int* poolctr = levctr + NT*32;              // NT

    hipMemsetAsync(levctr, 0, (NT*32 + NT)*sizeof(int), stream);
    phase1_k<<<NN/8, 256, 0, stream>>>(xs, rels, emb_W, rel_W,
                                       W_ix, b_ix, W_fx, b_fx, W_ox, W_ux,
                                       ix, fx, ox, ux);

    void* a_ci = (void*)child_idx; void* a_pi = (void*)parent_idx; void* a_nh = (void*)node_height;
    void* a_wih = (void*)W_ih; void* a_bih = (void*)b_ih;
    void* a_wfh = (void*)W_fh; void* a_bfh = (void*)b_fh;
    void* a_woh = (void*)W_oh; void* a_wuh = (void*)W_uh;
    void* a_ix = (void*)ix; void* a_fx = (void*)fx; void* a_ox = (void*)ox; void* a_ux = (void*)ux;
    void* a_h = (void*)h; void* a_lc = (void*)levctr;
    void* a_pb = (void*)poolbuf; void* a_pc = (void*)poolctr;
    void* a_wout = (void*)W_out; void* a_bout = (void*)b_out; void* a_out = d_out;

    void* args[] = { &a_ci, &a_pi, &a_nh,
                     &a_wih, &a_bih, &a_wfh, &a_bfh, &a_woh, &a_wuh,
                     &a_ix, &a_fx, &a_ox, &a_ux, &a_h, &a_lc,
                     &a_pb, &a_pc, &a_wout, &a_bout, &a_out };
    const unsigned int shmem = 4u * WC * CPAD * sizeof(float);   // 66560 B
    hipLaunchCooperativeKernel((const void*)tree_k, dim3(NT*CB), dim3(256),
                               args, shmem, stream);
}

// Round 7
// 410.949 us; speedup vs baseline: 2.4712x; 1.1232x over previous
//
#include <hip/hip_runtime.h>
#include <hip/hip_bf16.h>

// Problem constants (from reference)
#define NN   2048      // B*S nodes
#define BB   16
#define SS   128
#define HH   256       // hidden
#define DE   192
#define DR   64
#define DIN  256
#define LOUT 12
#define NLEV 21
#define TE   127       // edges per tree (S-1), contiguous slice per tree

#define NT   16        // trees
#define CB   16        // col-blocks per tree
#define WC   16        // columns per block
#define RB   16        // row slots (256 threads = RB x WC)
#define CPAD 260       // padded row stride (float4-aligned)
#define NCTR (NT*32 + NT)   // levctr + poolctr ints

typedef unsigned long long ull;

__device__ __forceinline__ float sigm(float x){ return 1.f/(1.f + __expf(-x)); }

__device__ __forceinline__ ull pack2(float a, float b){
    union { float f[2]; ull u; } v; v.f[0] = a; v.f[1] = b; return v.u;
}
__device__ __forceinline__ void unpack2(ull u, float& a, float& b){
    union { ull u; float f[2]; } v; v.u = u; a = v.f[0]; b = v.f[1];
}
// relaxed agent-scope (device-coherent, cache-bypassing) accessors
__device__ __forceinline__ void st_dev(ull* p, ull v){
    __hip_atomic_store(p, v, __ATOMIC_RELAXED, __HIP_MEMORY_SCOPE_AGENT);
}
__device__ __forceinline__ ull ld_dev(const ull* p){
    return __hip_atomic_load(p, __ATOMIC_RELAXED, __HIP_MEMORY_SCOPE_AGENT);
}
__device__ __forceinline__ void st_devf(float* p, float v){
    __hip_atomic_store(p, v, __ATOMIC_RELAXED, __HIP_MEMORY_SCOPE_AGENT);
}
__device__ __forceinline__ float ld_devf(const float* p){
    return __hip_atomic_load(p, __ATOMIC_RELAXED, __HIP_MEMORY_SCOPE_AGENT);
}
__device__ __forceinline__ int ld_devi(const int* p){
    return __hip_atomic_load(p, __ATOMIC_RELAXED, __HIP_MEMORY_SCOPE_AGENT);
}

// ---------------------------------------------------------------------------
// Phase 1: ix/fx/ox/ux = concat(emb,rel) @ W_* (+ b_*); 8 nodes/block. FP32.
// Block 0 additionally zeroes the dataflow counters for tree_k.
// ---------------------------------------------------------------------------
__global__ __launch_bounds__(256) void phase1_k(
    const int* __restrict__ xs, const int* __restrict__ rels,
    const float* __restrict__ emb_W, const float* __restrict__ rel_W,
    const float* __restrict__ W_ix, const float* __restrict__ b_ix,
    const float* __restrict__ W_fx, const float* __restrict__ b_fx,
    const float* __restrict__ W_ox, const float* __restrict__ W_ux,
    float* __restrict__ ix, float* __restrict__ fx,
    float* __restrict__ ox, float* __restrict__ ux,
    int* __restrict__ ctrs)
{
    const int t = threadIdx.x;
    const int node0 = blockIdx.x * 8;
    __shared__ float xc[8][DIN];

    if (blockIdx.x == 0) {
        for (int i = t; i < NCTR; i += 256) ctrs[i] = 0;
    }

    #pragma unroll
    for (int j = 0; j < 8; ++j) {
        int n = node0 + j;
        if (t < DE) {
            long long w = (long long)xs[n];
            xc[j][t] = emb_W[w * DE + t];
        } else {
            long long r = (long long)rels[n];
            xc[j][t] = rel_W[r * DR + (t - DE)];
        }
    }
    __syncthreads();

    float ai[8], af[8], ao[8], au[8];
    const float bi  = b_ix[t];
    const float bfv = b_fx[t];
    #pragma unroll
    for (int j = 0; j < 8; ++j) { ai[j] = bi; af[j] = bfv; ao[j] = 0.f; au[j] = 0.f; }

    for (int k = 0; k < DIN; k += 4) {
        float wi[4], wf[4], wo[4], wu[4];
        #pragma unroll
        for (int q = 0; q < 4; ++q) {
            wi[q] = W_ix[(k+q)*HH + t];
            wf[q] = W_fx[(k+q)*HH + t];
            wo[q] = W_ox[(k+q)*HH + t];
            wu[q] = W_ux[(k+q)*HH + t];
        }
        #pragma unroll
        for (int j = 0; j < 8; ++j) {
            float4 xv = *(const float4*)&xc[j][k];
            ai[j] += xv.x*wi[0] + xv.y*wi[1] + xv.z*wi[2] + xv.w*wi[3];
            af[j] += xv.x*wf[0] + xv.y*wf[1] + xv.z*wf[2] + xv.w*wf[3];
            ao[j] += xv.x*wo[0] + xv.y*wo[1] + xv.z*wo[2] + xv.w*wo[3];
            au[j] += xv.x*wu[0] + xv.y*wu[1] + xv.z*wu[2] + xv.w*wu[3];
        }
    }
    #pragma unroll
    for (int j = 0; j < 8; ++j) {
        int n = node0 + j;
        ix[n*HH + t] = ai[j];
        fx[n*HH + t] = af[j];
        ox[n*HH + t] = ao[j];
        ux[n*HH + t] = au[j];
    }
}

// ---------------------------------------------------------------------------
// Fence-free dataflow recurrence: 256 blocks = 16 trees x 16 col-blocks.
// ALL cross-block data (h exchange, poolbuf) moves via relaxed agent-scope
// atomics (device-coherent, cache-bypassing): no __threadfence anywhere.
// Release ordering = vmem drain at __syncthreads before the counter atomic.
// Thread map: cc = t&15 (column), rr = t>>4 (row slot 0..15).
// ---------------------------------------------------------------------------
__global__ __launch_bounds__(256, 1) void tree_k(
    const int* __restrict__ child_idx, const int* __restrict__ parent_idx,
    const int* __restrict__ node_height,
    const float* __restrict__ W_ih, const float* __restrict__ b_ih,
    const float* __restrict__ W_fh, const float* __restrict__ b_fh,
    const float* __restrict__ W_oh, const float* __restrict__ W_uh,
    const float* __restrict__ ix, const float* __restrict__ fx,
    const float* __restrict__ ox, const float* __restrict__ ux,
    ull* __restrict__ hx, int* __restrict__ levctr,
    float* __restrict__ poolbuf, int* __restrict__ poolctr,
    const float* __restrict__ W_out, const float* __restrict__ b_out,
    float* __restrict__ out)
{
    extern __shared__ float Wl[];            // [4][WC][CPAD] recurrent weights
    __shared__ float projL[4][SS][WC];       // ix,fx,ox,ux own-col slices
    __shared__ float cloc[SS][WC+1];         // cell state, never global
    __shared__ float hloc[SS][WC+1];         // own-col h, for pool + bulk store
    __shared__ float hstage[RB][CPAD];
    __shared__ float hsN[RB][CPAD];
    __shared__ float part[3*RB][WC+1];
    __shared__ float fcN[RB][WC+1];
    __shared__ float biasF[WC], biasI[WC];
    __shared__ int loff[SS+1], lcur[SS], llist[SS];
    __shared__ int lvoff[NLEV+1], lvcur[NLEV], lvnodes[SS];
    __shared__ int chs[RB], slts[RB], csum[RB+1], nodes_s[RB];
    __shared__ int s_maxH;

    const int t   = threadIdx.x;
    const int bid = blockIdx.x;
    // XCD-affine: tree b's 16 blocks all have bid % 8 == b % 8
    const int xcd  = bid & 7;
    const int idx  = bid >> 3;               // 0..31
    const int b    = xcd + 8 * (idx >> 4);   // tree
    const int cgp  = idx & 15;               // col group
    const int col0 = cgp * WC;
    const int cc   = t & 15;
    const int rr   = t >> 4;                 // 0..15

    // ---- build this tree's CSR + level lists in LDS (local node ids) ----
    if (t < SS)   lcur[t]  = 0;
    if (t < NLEV) lvcur[t] = 0;
    if (t == 0)   s_maxH   = 0;
    __syncthreads();
    if (t < TE) { int p = parent_idx[b*TE + t] - b*SS; atomicAdd(&lcur[p], 1); }
    if (t < SS) { int hg = node_height[b*SS + t]; atomicAdd(&lvcur[hg], 1); atomicMax(&s_maxH, hg); }
    __syncthreads();
    if (t == 0) {
        int off = 0;
        for (int i = 0; i < SS; ++i) { int v = lcur[i]; loff[i] = off; lcur[i] = off; off += v; }
        loff[SS] = off;
        off = 0;
        for (int l = 0; l < NLEV; ++l) { int v = lvcur[l]; lvoff[l] = off; lvcur[l] = off; off += v; }
        lvoff[NLEV] = off;
    }
    __syncthreads();
    if (t < TE) {
        int e = b*TE + t;
        int p = parent_idx[e] - b*SS;
        int pos = atomicAdd(&lcur[p], 1);
        llist[pos] = child_idx[e] - b*SS;
    }
    if (t < SS) {
        int hg = node_height[b*SS + t];
        int pos = atomicAdd(&lvcur[hg], 1);
        lvnodes[pos] = t;
    }

    // ---- load recurrent weight slices into LDS (fh, ih, oh, uh) ----
    {
        const float* Wm[4] = { W_fh, W_ih, W_oh, W_uh };
        for (int m = 0; m < 4; ++m) {
            float* dst = Wl + (m*WC + cc)*CPAD;
            const float* src = Wm[m] + col0 + cc;
            #pragma unroll 4
            for (int kb = 0; kb < 16; ++kb) {
                int k = kb*16 + rr;
                dst[k] = src[(long long)k*HH];
            }
        }
        if (t < WC) { biasF[t] = b_fh[col0+t]; biasI[t] = b_ih[col0+t]; }
    }

    // ---- preload proj slices into LDS ----
    {
        const float* P[4] = { ix, fx, ox, ux };
        for (int m = 0; m < 4; ++m) {
            #pragma unroll
            for (int base = 0; base < 512; base += 256) {
                int i = base + t;                 // float4 index
                int n = i >> 2, q = i & 3;
                *(float4*)&projL[m][n][q*4] =
                    *(const float4*)&P[m][(long long)(b*SS + n)*HH + col0 + q*4];
            }
        }
    }
    __syncthreads();

    // ---- bottom-up levels (0 = leaves) ----
    const int mH = s_maxH;
    for (int lev = 0; lev <= mH; ++lev) {
        if (lev > 0) {
            if (t == 0) {
                while (ld_devi(&levctr[b*32 + lev - 1]) < CB)
                    __builtin_amdgcn_s_sleep(1);
            }
            __syncthreads();
        }

        const int s0 = lvoff[lev], s1 = lvoff[lev+1];
        for (int cs = s0; cs < s1; cs += RB) {
            const int nbN = min(RB, s1 - cs);

            if (lev == 0) {
                if (rr < nbN) {
                    int n = lvnodes[cs + rr];
                    float iv = sigm(projL[0][n][cc] + biasI[cc]);
                    float ov = sigm(projL[2][n][cc]);
                    float uv = tanhf(projL[3][n][cc]);
                    float cv = iv * uv;
                    cloc[n][cc] = cv;
                    hloc[n][cc] = ov * tanhf(cv);
                }
                continue;
            }

            if (t < nbN) {
                int n = lvnodes[cs + t];
                nodes_s[t] = n;
                csum[t+1]  = loff[n+1] - loff[n];
            }
            if (t == 0) csum[0] = 0;
            __syncthreads();
            if (t == 0) for (int i = 1; i <= nbN; ++i) csum[i] += csum[i-1];
            for (int r2 = 0; r2 < nbN; ++r2) hsN[r2][t] = 0.f;
            fcN[rr][cc] = 0.f;
            __syncthreads();

            const int Ech = csum[nbN];
            for (int eb = 0; eb < Ech; eb += RB) {
                const int m = min(RB, Ech - eb);
                if (t < m) {
                    int e = eb + t;
                    int s2 = 0;
                    while (csum[s2+1] <= e) ++s2;
                    chs[t]  = llist[loff[nodes_s[s2]] + (e - csum[s2])];
                    slts[t] = s2;
                }
                __syncthreads();
                // stage child h rows via device-coherent packed loads
                if (rr < m) {
                    const ull* src = hx + (((long long)(b*SS + chs[rr]))*HH + cc*16)/2;
                    float* dst = &hstage[rr][cc*16];
                    #pragma unroll
                    for (int q = 0; q < 8; ++q) {
                        float a, bb;
                        unpack2(ld_dev(&src[q]), a, bb);
                        dst[2*q]   = a;
                        dst[2*q+1] = bb;
                    }
                }
                __syncthreads();
                for (int jj = 0; jj < m; ++jj)
                    hsN[slts[jj]][t] += hstage[jj][t];
                const int nb = (m<=1)?1:(m<=2)?2:(m<=4)?4:(m<=8)?8:16;
                {
                    int slot = rr % nb;
                    int ksl  = rr / nb;
                    float d = 0.f;
                    if (slot < m) {
                        const float* wf = Wl + (0*WC + cc)*CPAD;
                        const float* hr = hstage[slot];
                        int k0 = ksl * (16*nb), k1 = k0 + 16*nb;
                        for (int k = k0; k < k1; k += 4) {
                            float4 w4 = *(const float4*)(wf + k);
                            float4 h4 = *(const float4*)(hr + k);
                            d += w4.x*h4.x + w4.y*h4.y + w4.z*h4.z + w4.w*h4.w;
                        }
                    }
                    part[rr][cc] = d;
                }
                __syncthreads();
                if (rr < m) {
                    float d = 0.f;
                    for (int j = rr; j < RB; j += nb) d += part[j][cc];
                    float f = sigm(d + biasF[cc] + projL[1][nodes_s[slts[rr]]][cc]);
                    atomicAdd(&fcN[slts[rr]][cc], f * cloc[chs[rr]][cc]);
                }
                __syncthreads();
            }

            // i/o/u dots over hsum, depth-adaptive
            {
                const int nb2 = (nbN<=1)?1:(nbN<=2)?2:(nbN<=4)?4:(nbN<=8)?8:16;
                int slot = rr % nb2;
                int ksl  = rr / nb2;
                int k0 = ksl * (16*nb2), k1 = k0 + 16*nb2;
                for (int mat = 0; mat < 3; ++mat) {
                    float d = 0.f;
                    if (slot < nbN) {
                        const float* wm = Wl + ((1+mat)*WC + cc)*CPAD;
                        const float* hr = hsN[slot];
                        for (int k = k0; k < k1; k += 4) {
                            float4 w4 = *(const float4*)(wm + k);
                            float4 h4 = *(const float4*)(hr + k);
                            d += w4.x*h4.x + w4.y*h4.y + w4.z*h4.z + w4.w*h4.w;
                        }
                    }
                    part[mat*RB + rr][cc] = d;
                }
                __syncthreads();
                if (rr < nbN) {
                    float di = 0.f, dof = 0.f, du = 0.f;
                    for (int j = rr; j < RB; j += nb2) {
                        di  += part[0*RB + j][cc];
                        dof += part[1*RB + j][cc];
                        du  += part[2*RB + j][cc];
                    }
                    int n = nodes_s[rr];
                    float iv = sigm(projL[0][n][cc] + di + biasI[cc]);
                    float ov = sigm(projL[2][n][cc] + dof);
                    float uv = tanhf(projL[3][n][cc] + du);
                    float cv = iv*uv + fcN[rr][cc];
                    cloc[n][cc] = cv;
                    hloc[n][cc] = ov * tanhf(cv);
                }
                __syncthreads();
            }
        }

        // ---- bulk-publish this level's h (packed device-coherent stores) ----
        __syncthreads();
        {
            const int L = s1 - s0;
            for (int i = t; i < L*8; i += 256) {
                int n = lvnodes[s0 + (i >> 3)];
                int p = i & 7;
                ull u = pack2(hloc[n][2*p], hloc[n][2*p+1]);
                st_dev(&hx[(((long long)(b*SS + n))*HH + col0)/2 + p], u);
            }
        }
        __syncthreads();                     // drain stores before release
        if (t == 0) atomicAdd(&levctr[b*32 + lev], 1);
    }

    // ---- max-pool own columns from LDS, exchange, cgp==0 emits output ----
    {
        float mx = -3.4e38f;
        for (int s2 = rr; s2 < SS; s2 += RB)
            mx = fmaxf(mx, hloc[s2][cc]);
        part[rr][cc] = mx;
        __syncthreads();
        if (t < WC) {
            float m2 = part[0][t];
            #pragma unroll
            for (int r2 = 1; r2 < RB; ++r2) m2 = fmaxf(m2, part[r2][t]);
            st_devf(&poolbuf[b*HH + col0 + t], m2);
        }
        __syncthreads();                     // drain poolbuf stores
        if (t == 0) atomicAdd(&poolctr[b], 1);
    }
    if (cgp == 0) {
        if (t == 0) {
            while (ld_devi(&poolctr[b]) < CB)
                __builtin_amdgcn_s_sleep(1);
        }
        __syncthreads();
        float* pl = hstage[0];               // 260 >= 256 floats, reuse
        pl[t] = ld_devf(&poolbuf[b*HH + t]);
        __syncthreads();
        if (t < LOUT) {
            float acc = b_out[t];
            for (int k = 0; k < HH; ++k)
                acc += pl[k] * W_out[k*LOUT + t];
            out[b*LOUT + t] = acc;
        }
    }
}

// ---------------------------------------------------------------------------
extern "C" void kernel_launch(void* const* d_in, const int* in_sizes, int n_in,
                              void* d_out, int out_size, void* d_ws, size_t ws_size,
                              hipStream_t stream)
{
    const int* xs          = (const int*)d_in[0];
    const int* rels        = (const int*)d_in[1];
    const int* child_idx   = (const int*)d_in[2];
    const int* parent_idx  = (const int*)d_in[3];
    const int* node_height = (const int*)d_in[4];
    // d_in[5] = n_levels (hardcoded NLEV)
    const float* emb_W = (const float*)d_in[6];
    const float* rel_W = (const float*)d_in[7];
    const float* W_ix  = (const float*)d_in[8];
    const float* b_ix  = (const float*)d_in[9];
    const float* W_ih  = (const float*)d_in[10];
    const float* b_ih  = (const float*)d_in[11];
    const float* W_fx  = (const float*)d_in[12];
    const float* b_fx  = (const float*)d_in[13];
    const float* W_fh  = (const float*)d_in[14];
    const float* b_fh  = (const float*)d_in[15];
    const float* W_ox  = (const float*)d_in[16];
    const float* W_oh  = (const float*)d_in[17];
    const float* W_ux  = (const float*)d_in[18];
    const float* W_uh  = (const float*)d_in[19];
    const float* W_out = (const float*)d_in[20];
    const float* b_out = (const float*)d_in[21];

    const size_t NH = (size_t)NN * HH;
    float* ix = (float*)d_ws;
    float* fx = ix + NH;
    float* ox = fx + NH;
    float* ux = ox + NH;
    float* h  = ux + NH;                        // exchanged as ull pairs
    float* poolbuf = h + NH;                    // BB*HH floats
    int* levctr  = (int*)(poolbuf + BB*HH);     // NT*32
    int* poolctr = levctr + NT*32;              // NT

    phase1_k<<<NN/8, 256, 0, stream>>>(xs, rels, emb_W, rel_W,
                                       W_ix, b_ix, W_fx, b_fx, W_ox, W_ux,
                                       ix, fx, ox, ux, levctr);

    void* a_ci = (void*)child_idx; void* a_pi = (void*)parent_idx; void* a_nh = (void*)node_height;
    void* a_wih = (void*)W_ih; void* a_bih = (void*)b_ih;
    void* a_wfh = (void*)W_fh; void* a_bfh = (void*)b_fh;
    void* a_woh = (void*)W_oh; void* a_wuh = (void*)W_uh;
    void* a_ix = (void*)ix; void* a_fx = (void*)fx; void* a_ox = (void*)ox; void* a_ux = (void*)ux;
    void* a_h = (void*)h; void* a_lc = (void*)levctr;
    void* a_pb = (void*)poolbuf; void* a_pc = (void*)poolctr;
    void* a_wout = (void*)W_out; void* a_bout = (void*)b_out; void* a_out = d_out;

    void* args[] = { &a_ci, &a_pi, &a_nh,
                     &a_wih, &a_bih, &a_wfh, &a_bfh, &a_woh, &a_wuh,
                     &a_ix, &a_fx, &a_ox, &a_ux, &a_h, &a_lc,
                     &a_pb, &a_pc, &a_wout, &a_bout, &a_out };
    const unsigned int shmem = 4u * WC * CPAD * sizeof(float);   // 66560 B
    hipLaunchCooperativeKernel((const void*)tree_k, dim3(NT*CB), dim3(256),
                               args, shmem, stream);
}

// Round 8
// 386.288 us; speedup vs baseline: 2.6289x; 1.0638x over previous
//
#include <hip/hip_runtime.h>
#include <hip/hip_bf16.h>

// Problem constants (from reference)
#define NN   2048      // B*S nodes
#define BB   16
#define SS   128
#define HH   256       // hidden
#define DE   192
#define DR   64
#define DIN  256
#define LOUT 12
#define NLEV 21
#define TE   127       // edges per tree (S-1), contiguous slice per tree

#define NT   16        // trees
#define CB   16        // col-blocks per tree
#define WC   16        // columns per block
#define RB   16        // row slots (256 threads = RB x WC)
#define CPAD 260       // padded row stride (float4-aligned)
#define NCTR (NT*32 + NT)   // levctr + poolctr ints

typedef unsigned long long ull;

__device__ __forceinline__ float sigm(float x){ return 1.f/(1.f + __expf(-x)); }

__device__ __forceinline__ ull pack2(float a, float b){
    union { float f[2]; ull u; } v; v.f[0] = a; v.f[1] = b; return v.u;
}
__device__ __forceinline__ void unpack2(ull u, float& a, float& b){
    union { ull u; float f[2]; } v; v.u = u; a = v.f[0]; b = v.f[1];
}
// relaxed agent-scope (device-coherent, cache-bypassing) accessors
__device__ __forceinline__ void st_dev(ull* p, ull v){
    __hip_atomic_store(p, v, __ATOMIC_RELAXED, __HIP_MEMORY_SCOPE_AGENT);
}
__device__ __forceinline__ ull ld_dev(const ull* p){
    return __hip_atomic_load(p, __ATOMIC_RELAXED, __HIP_MEMORY_SCOPE_AGENT);
}
__device__ __forceinline__ void st_devf(float* p, float v){
    __hip_atomic_store(p, v, __ATOMIC_RELAXED, __HIP_MEMORY_SCOPE_AGENT);
}
__device__ __forceinline__ float ld_devf(const float* p){
    return __hip_atomic_load(p, __ATOMIC_RELAXED, __HIP_MEMORY_SCOPE_AGENT);
}
__device__ __forceinline__ int ld_devi(const int* p){
    return __hip_atomic_load(p, __ATOMIC_RELAXED, __HIP_MEMORY_SCOPE_AGENT);
}

// ---------------------------------------------------------------------------
// Phase 1: ix/fx/ox/ux = concat(emb,rel) @ W_* (+ b_*); 8 nodes/block. FP32.
// Block 0 additionally zeroes the dataflow counters for tree_k.
// ---------------------------------------------------------------------------
__global__ __launch_bounds__(256) void phase1_k(
    const int* __restrict__ xs, const int* __restrict__ rels,
    const float* __restrict__ emb_W, const float* __restrict__ rel_W,
    const float* __restrict__ W_ix, const float* __restrict__ b_ix,
    const float* __restrict__ W_fx, const float* __restrict__ b_fx,
    const float* __restrict__ W_ox, const float* __restrict__ W_ux,
    float* __restrict__ ix, float* __restrict__ fx,
    float* __restrict__ ox, float* __restrict__ ux,
    int* __restrict__ ctrs)
{
    const int t = threadIdx.x;
    const int node0 = blockIdx.x * 8;
    __shared__ float xc[8][DIN];

    if (blockIdx.x == 0) {
        for (int i = t; i < NCTR; i += 256) ctrs[i] = 0;
    }

    #pragma unroll
    for (int j = 0; j < 8; ++j) {
        int n = node0 + j;
        if (t < DE) {
            long long w = (long long)xs[n];
            xc[j][t] = emb_W[w * DE + t];
        } else {
            long long r = (long long)rels[n];
            xc[j][t] = rel_W[r * DR + (t - DE)];
        }
    }
    __syncthreads();

    float ai[8], af[8], ao[8], au[8];
    const float bi  = b_ix[t];
    const float bfv = b_fx[t];
    #pragma unroll
    for (int j = 0; j < 8; ++j) { ai[j] = bi; af[j] = bfv; ao[j] = 0.f; au[j] = 0.f; }

    for (int k = 0; k < DIN; k += 4) {
        float wi[4], wf[4], wo[4], wu[4];
        #pragma unroll
        for (int q = 0; q < 4; ++q) {
            wi[q] = W_ix[(k+q)*HH + t];
            wf[q] = W_fx[(k+q)*HH + t];
            wo[q] = W_ox[(k+q)*HH + t];
            wu[q] = W_ux[(k+q)*HH + t];
        }
        #pragma unroll
        for (int j = 0; j < 8; ++j) {
            float4 xv = *(const float4*)&xc[j][k];
            ai[j] += xv.x*wi[0] + xv.y*wi[1] + xv.z*wi[2] + xv.w*wi[3];
            af[j] += xv.x*wf[0] + xv.y*wf[1] + xv.z*wf[2] + xv.w*wf[3];
            ao[j] += xv.x*wo[0] + xv.y*wo[1] + xv.z*wo[2] + xv.w*wo[3];
            au[j] += xv.x*wu[0] + xv.y*wu[1] + xv.z*wu[2] + xv.w*wu[3];
        }
    }
    #pragma unroll
    for (int j = 0; j < 8; ++j) {
        int n = node0 + j;
        ix[n*HH + t] = ai[j];
        fx[n*HH + t] = af[j];
        ox[n*HH + t] = ao[j];
        ux[n*HH + t] = au[j];
    }
}

// ---------------------------------------------------------------------------
// Fence-free dataflow recurrence: 256 blocks = 16 trees x 16 col-blocks.
// Cross-block data via relaxed agent-scope atomics; per-(tree,level) counters.
// Fast path for single-node levels: wave-mapped dots, shfl reductions,
// ~5 barriers/level. Generic chunk path for multi-node levels.
// Thread map (generic): cc = t&15 (column), rr = t>>4 (row slot 0..15).
// ---------------------------------------------------------------------------
__global__ __launch_bounds__(256, 1) void tree_k(
    const int* __restrict__ child_idx, const int* __restrict__ parent_idx,
    const int* __restrict__ node_height,
    const float* __restrict__ W_ih, const float* __restrict__ b_ih,
    const float* __restrict__ W_fh, const float* __restrict__ b_fh,
    const float* __restrict__ W_oh, const float* __restrict__ W_uh,
    const float* __restrict__ ix, const float* __restrict__ fx,
    const float* __restrict__ ox, const float* __restrict__ ux,
    ull* __restrict__ hx, int* __restrict__ levctr,
    float* __restrict__ poolbuf, int* __restrict__ poolctr,
    const float* __restrict__ W_out, const float* __restrict__ b_out,
    float* __restrict__ out)
{
    extern __shared__ float Wl[];            // [4][WC][CPAD] recurrent weights
    __shared__ float projL[4][SS][WC];       // ix,fx,ox,ux own-col slices
    __shared__ float cloc[SS][WC+1];         // cell state, never global
    __shared__ float hloc[SS][WC+1];         // own-col h, for pool + bulk store
    __shared__ float hstage[RB][CPAD];
    __shared__ float hsN[RB][CPAD];
    __shared__ float part[3*RB][WC+1];
    __shared__ float fcN[RB][WC+1];
    __shared__ float biasF[WC], biasI[WC];
    __shared__ int loff[SS+1], lcur[SS], llist[SS];
    __shared__ int lvoff[NLEV+1], lvcur[NLEV], lvnodes[SS];
    __shared__ int chs[RB], slts[RB], csum[RB+1], nodes_s[RB];
    __shared__ int s_maxH;

    const int t   = threadIdx.x;
    const int bid = blockIdx.x;
    // XCD-affine: tree b's 16 blocks all have bid % 8 == b % 8
    const int xcd  = bid & 7;
    const int idx  = bid >> 3;               // 0..31
    const int b    = xcd + 8 * (idx >> 4);   // tree
    const int cgp  = idx & 15;               // col group
    const int col0 = cgp * WC;
    const int cc   = t & 15;
    const int rr   = t >> 4;                 // 0..15

    // ---- build this tree's CSR + level lists in LDS (local node ids) ----
    if (t < SS)   lcur[t]  = 0;
    if (t < NLEV) lvcur[t] = 0;
    if (t == 0)   s_maxH   = 0;
    __syncthreads();
    if (t < TE) { int p = parent_idx[b*TE + t] - b*SS; atomicAdd(&lcur[p], 1); }
    if (t < SS) { int hg = node_height[b*SS + t]; atomicAdd(&lvcur[hg], 1); atomicMax(&s_maxH, hg); }
    __syncthreads();
    if (t == 0) {
        int off = 0;
        for (int i = 0; i < SS; ++i) { int v = lcur[i]; loff[i] = off; lcur[i] = off; off += v; }
        loff[SS] = off;
        off = 0;
        for (int l = 0; l < NLEV; ++l) { int v = lvcur[l]; lvoff[l] = off; lvcur[l] = off; off += v; }
        lvoff[NLEV] = off;
    }
    __syncthreads();
    if (t < TE) {
        int e = b*TE + t;
        int p = parent_idx[e] - b*SS;
        int pos = atomicAdd(&lcur[p], 1);
        llist[pos] = child_idx[e] - b*SS;
    }
    if (t < SS) {
        int hg = node_height[b*SS + t];
        int pos = atomicAdd(&lvcur[hg], 1);
        lvnodes[pos] = t;
    }

    // ---- load recurrent weight slices into LDS (fh, ih, oh, uh) ----
    {
        const float* Wm[4] = { W_fh, W_ih, W_oh, W_uh };
        for (int m = 0; m < 4; ++m) {
            float* dst = Wl + (m*WC + cc)*CPAD;
            const float* src = Wm[m] + col0 + cc;
            #pragma unroll 4
            for (int kb = 0; kb < 16; ++kb) {
                int k = kb*16 + rr;
                dst[k] = src[(long long)k*HH];
            }
        }
        if (t < WC) { biasF[t] = b_fh[col0+t]; biasI[t] = b_ih[col0+t]; }
    }

    // ---- preload proj slices into LDS ----
    {
        const float* P[4] = { ix, fx, ox, ux };
        for (int m = 0; m < 4; ++m) {
            #pragma unroll
            for (int base = 0; base < 512; base += 256) {
                int i = base + t;                 // float4 index
                int n = i >> 2, q = i & 3;
                *(float4*)&projL[m][n][q*4] =
                    *(const float4*)&P[m][(long long)(b*SS + n)*HH + col0 + q*4];
            }
        }
    }
    __syncthreads();

    // ---- bottom-up levels (0 = leaves) ----
    const int mH = s_maxH;
    for (int lev = 0; lev <= mH; ++lev) {
        if (lev > 0) {
            // all-thread poll: no barrier needed, each thread confirms
            while (ld_devi(&levctr[b*32 + lev - 1]) < CB)
                __builtin_amdgcn_s_sleep(1);
        }

        const int s0 = lvoff[lev], s1 = lvoff[lev+1];

        if (lev > 0 && s1 - s0 == 1) {
            // ================= fast path: single node =================
            const int n  = lvnodes[s0];
            const int off = loff[n];
            const int E  = loff[n+1] - off;
            if (E <= RB) {
                if (t < E)  chs[t] = llist[off + t];
                if (t < WC) fcN[0][t] = 0.f;
                __syncthreads();
                // stage all E child rows (packed coherent loads)
                for (int i = t; i < E*128; i += 256) {
                    int e = i >> 7, j = i & 127;
                    float a, bb;
                    unpack2(ld_dev(&hx[((long long)(b*SS + chs[e]))*HH/2 + j]), a, bb);
                    hstage[e][2*j]   = a;
                    hstage[e][2*j+1] = bb;
                }
                __syncthreads();
                // hsum into hsN[0]
                {
                    float s = 0.f;
                    for (int e = 0; e < E; ++e) s += hstage[e][t];
                    hsN[0][t] = s;
                }
                __syncthreads();
                // dots: rows 0..E-1 = f per edge, E..E+2 = i/o/u on hsum.
                // wave w owns row p0+w; lane: cc = t&15, ksl = (t>>4)&3 (dot-64);
                // reduce across ksl via shfl_xor (intra-wave, no barriers).
                const int wv   = t >> 6;
                const int ksl4 = (t >> 4) & 3;
                const int nrows = E + 3;
                for (int p0 = 0; p0 < nrows; p0 += 4) {
                    int r = p0 + wv;
                    float d = 0.f;
                    if (r < nrows) {
                        const float* hr = (r < E) ? hstage[r] : hsN[0];
                        int mat = (r < E) ? 0 : (1 + (r - E));
                        const float* wm = Wl + (mat*WC + cc)*CPAD + ksl4*64;
                        const float* hh = hr + ksl4*64;
                        #pragma unroll 8
                        for (int k = 0; k < 64; k += 4) {
                            float4 w4 = *(const float4*)(wm + k);
                            float4 h4 = *(const float4*)(hh + k);
                            d += w4.x*h4.x + w4.y*h4.y + w4.z*h4.z + w4.w*h4.w;
                        }
                    }
                    d += __shfl_xor(d, 16);
                    d += __shfl_xor(d, 32);
                    if (r < nrows && ksl4 == 0) {
                        if (r < E) {
                            float f = sigm(d + biasF[cc] + projL[1][n][cc]);
                            atomicAdd(&fcN[0][cc], f * cloc[chs[r]][cc]);
                        } else {
                            part[r - E][cc] = d;
                        }
                    }
                }
                __syncthreads();
                if (t < WC) {
                    float iv = sigm(projL[0][n][t] + part[0][t] + biasI[t]);
                    float ov = sigm(projL[2][n][t] + part[1][t]);
                    float uv = tanhf(projL[3][n][t] + part[2][t]);
                    float cv = iv*uv + fcN[0][t];
                    cloc[n][t] = cv;
                    hloc[n][t] = ov * tanhf(cv);
                }
                goto publish;   // common publish below
            }
            // E > RB: fall through to generic path
        }

        for (int cs = s0; cs < s1; cs += RB) {
            const int nbN = min(RB, s1 - cs);

            if (lev == 0) {
                if (rr < nbN) {
                    int n = lvnodes[cs + rr];
                    float iv = sigm(projL[0][n][cc] + biasI[cc]);
                    float ov = sigm(projL[2][n][cc]);
                    float uv = tanhf(projL[3][n][cc]);
                    float cv = iv * uv;
                    cloc[n][cc] = cv;
                    hloc[n][cc] = ov * tanhf(cv);
                }
                continue;
            }

            if (t < nbN) {
                int n = lvnodes[cs + t];
                nodes_s[t] = n;
                csum[t+1]  = loff[n+1] - loff[n];
            }
            if (t == 0) csum[0] = 0;
            __syncthreads();
            if (t == 0) for (int i = 1; i <= nbN; ++i) csum[i] += csum[i-1];
            for (int r2 = 0; r2 < nbN; ++r2) hsN[r2][t] = 0.f;
            fcN[rr][cc] = 0.f;
            __syncthreads();

            const int Ech = csum[nbN];
            for (int eb = 0; eb < Ech; eb += RB) {
                const int m = min(RB, Ech - eb);
                if (t < m) {
                    int e = eb + t;
                    int s2 = 0;
                    while (csum[s2+1] <= e) ++s2;
                    chs[t]  = llist[loff[nodes_s[s2]] + (e - csum[s2])];
                    slts[t] = s2;
                }
                __syncthreads();
                // stage child h rows: packed loads -> float4 LDS writes
                if (rr < m) {
                    const ull* src = hx + (((long long)(b*SS + chs[rr]))*HH + cc*16)/2;
                    float* dst = &hstage[rr][cc*16];
                    ull u[8];
                    #pragma unroll
                    for (int q = 0; q < 8; ++q) u[q] = ld_dev(&src[q]);
                    #pragma unroll
                    for (int q = 0; q < 4; ++q) {
                        float4 v;
                        unpack2(u[2*q],   v.x, v.y);
                        unpack2(u[2*q+1], v.z, v.w);
                        *(float4*)(dst + q*4) = v;
                    }
                }
                __syncthreads();
                for (int jj = 0; jj < m; ++jj)
                    hsN[slts[jj]][t] += hstage[jj][t];
                const int nb = (m<=1)?1:(m<=2)?2:(m<=4)?4:(m<=8)?8:16;
                {
                    int slot = rr % nb;
                    int ksl  = rr / nb;
                    float d = 0.f;
                    if (slot < m) {
                        const float* wf = Wl + (0*WC + cc)*CPAD;
                        const float* hr = hstage[slot];
                        int k0 = ksl * (16*nb), k1 = k0 + 16*nb;
                        for (int k = k0; k < k1; k += 4) {
                            float4 w4 = *(const float4*)(wf + k);
                            float4 h4 = *(const float4*)(hr + k);
                            d += w4.x*h4.x + w4.y*h4.y + w4.z*h4.z + w4.w*h4.w;
                        }
                    }
                    part[rr][cc] = d;
                }
                __syncthreads();
                if (rr < m) {
                    float d = 0.f;
                    for (int j = rr; j < RB; j += nb) d += part[j][cc];
                    float f = sigm(d + biasF[cc] + projL[1][nodes_s[slts[rr]]][cc]);
                    atomicAdd(&fcN[slts[rr]][cc], f * cloc[chs[rr]][cc]);
                }
                __syncthreads();
            }

            // i/o/u dots over hsum, depth-adaptive
            {
                const int nb2 = (nbN<=1)?1:(nbN<=2)?2:(nbN<=4)?4:(nbN<=8)?8:16;
                int slot = rr % nb2;
                int ksl  = rr / nb2;
                int k0 = ksl * (16*nb2), k1 = k0 + 16*nb2;
                for (int mat = 0; mat < 3; ++mat) {
                    float d = 0.f;
                    if (slot < nbN) {
                        const float* wm = Wl + ((1+mat)*WC + cc)*CPAD;
                        const float* hr = hsN[slot];
                        for (int k = k0; k < k1; k += 4) {
                            float4 w4 = *(const float4*)(wm + k);
                            float4 h4 = *(const float4*)(hr + k);
                            d += w4.x*h4.x + w4.y*h4.y + w4.z*h4.z + w4.w*h4.w;
                        }
                    }
                    part[mat*RB + rr][cc] = d;
                }
                __syncthreads();
                if (rr < nbN) {
                    float di = 0.f, dof = 0.f, du = 0.f;
                    for (int j = rr; j < RB; j += nb2) {
                        di  += part[0*RB + j][cc];
                        dof += part[1*RB + j][cc];
                        du  += part[2*RB + j][cc];
                    }
                    int n = nodes_s[rr];
                    float iv = sigm(projL[0][n][cc] + di + biasI[cc]);
                    float ov = sigm(projL[2][n][cc] + dof);
                    float uv = tanhf(projL[3][n][cc] + du);
                    float cv = iv*uv + fcN[rr][cc];
                    cloc[n][cc] = cv;
                    hloc[n][cc] = ov * tanhf(cv);
                }
                __syncthreads();
            }
        }

publish:
        // ---- bulk-publish this level's h (packed device-coherent stores) ----
        __syncthreads();
        {
            const int L = s1 - s0;
            for (int i = t; i < L*8; i += 256) {
                int n = lvnodes[s0 + (i >> 3)];
                int p = i & 7;
                ull u = pack2(hloc[n][2*p], hloc[n][2*p+1]);
                st_dev(&hx[(((long long)(b*SS + n))*HH + col0)/2 + p], u);
            }
        }
        __syncthreads();                     // drain stores before release
        if (t == 0) atomicAdd(&levctr[b*32 + lev], 1);
    }

    // ---- max-pool own columns from LDS, exchange, cgp==0 emits output ----
    {
        float mx = -3.4e38f;
        for (int s2 = rr; s2 < SS; s2 += RB)
            mx = fmaxf(mx, hloc[s2][cc]);
        part[rr][cc] = mx;
        __syncthreads();
        if (t < WC) {
            float m2 = part[0][t];
            #pragma unroll
            for (int r2 = 1; r2 < RB; ++r2) m2 = fmaxf(m2, part[r2][t]);
            st_devf(&poolbuf[b*HH + col0 + t], m2);
        }
        __syncthreads();                     // drain poolbuf stores
        if (t == 0) atomicAdd(&poolctr[b], 1);
    }
    if (cgp == 0) {
        while (ld_devi(&poolctr[b]) < CB)
            __builtin_amdgcn_s_sleep(1);
        float* pl = hstage[0];               // 260 >= 256 floats, reuse
        pl[t] = ld_devf(&poolbuf[b*HH + t]);
        __syncthreads();
        if (t < LOUT) {
            float acc = b_out[t];
            for (int k = 0; k < HH; ++k)
                acc += pl[k] * W_out[k*LOUT + t];
            out[b*LOUT + t] = acc;
        }
    }
}

// ---------------------------------------------------------------------------
extern "C" void kernel_launch(void* const* d_in, const int* in_sizes, int n_in,
                              void* d_out, int out_size, void* d_ws, size_t ws_size,
                              hipStream_t stream)
{
    const int* xs          = (const int*)d_in[0];
    const int* rels        = (const int*)d_in[1];
    const int* child_idx   = (const int*)d_in[2];
    const int* parent_idx  = (const int*)d_in[3];
    const int* node_height = (const int*)d_in[4];
    // d_in[5] = n_levels (hardcoded NLEV)
    const float* emb_W = (const float*)d_in[6];
    const float* rel_W = (const float*)d_in[7];
    const float* W_ix  = (const float*)d_in[8];
    const float* b_ix  = (const float*)d_in[9];
    const float* W_ih  = (const float*)d_in[10];
    const float* b_ih  = (const float*)d_in[11];
    const float* W_fx  = (const float*)d_in[12];
    const float* b_fx  = (const float*)d_in[13];
    const float* W_fh  = (const float*)d_in[14];
    const float* b_fh  = (const float*)d_in[15];
    const float* W_ox  = (const float*)d_in[16];
    const float* W_oh  = (const float*)d_in[17];
    const float* W_ux  = (const float*)d_in[18];
    const float* W_uh  = (const float*)d_in[19];
    const float* W_out = (const float*)d_in[20];
    const float* b_out = (const float*)d_in[21];

    const size_t NH = (size_t)NN * HH;
    float* ix = (float*)d_ws;
    float* fx = ix + NH;
    float* ox = fx + NH;
    float* ux = ox + NH;
    float* h  = ux + NH;                        // exchanged as ull pairs
    float* poolbuf = h + NH;                    // BB*HH floats
    int* levctr  = (int*)(poolbuf + BB*HH);     // NT*32
    int* poolctr = levctr + NT*32;              // NT

    phase1_k<<<NN/8, 256, 0, stream>>>(xs, rels, emb_W, rel_W,
                                       W_ix, b_ix, W_fx, b_fx, W_ox, W_ux,
                                       ix, fx, ox, ux, levctr);

    void* a_ci = (void*)child_idx; void* a_pi = (void*)parent_idx; void* a_nh = (void*)node_height;
    void* a_wih = (void*)W_ih; void* a_bih = (void*)b_ih;
    void* a_wfh = (void*)W_fh; void* a_bfh = (void*)b_fh;
    void* a_woh = (void*)W_oh; void* a_wuh = (void*)W_uh;
    void* a_ix = (void*)ix; void* a_fx = (void*)fx; void* a_ox = (void*)ox; void* a_ux = (void*)ux;
    void* a_h = (void*)h; void* a_lc = (void*)levctr;
    void* a_pb = (void*)poolbuf; void* a_pc = (void*)poolctr;
    void* a_wout = (void*)W_out; void* a_bout = (void*)b_out; void* a_out = d_out;

    void* args[] = { &a_ci, &a_pi, &a_nh,
                     &a_wih, &a_bih, &a_wfh, &a_bfh, &a_woh, &a_wuh,
                     &a_ix, &a_fx, &a_ox, &a_ux, &a_h, &a_lc,
                     &a_pb, &a_pc, &a_wout, &a_bout, &a_out };
    const unsigned int shmem = 4u * WC * CPAD * sizeof(float);   // 66560 B
    hipLaunchCooperativeKernel((const void*)tree_k, dim3(NT*CB), dim3(256),
                               args, shmem, stream);
}

// Round 9
// 343.993 us; speedup vs baseline: 2.9522x; 1.1230x over previous
//
#include <hip/hip_runtime.h>
#include <hip/hip_bf16.h>

// Problem constants (from reference)
#define NN   2048      // B*S nodes
#define BB   16
#define SS   128
#define HH   256       // hidden
#define DE   192
#define DR   64
#define DIN  256
#define LOUT 12
#define NLEV 21
#define TE   127       // edges per tree (S-1), contiguous slice per tree

#define NT   16        // trees
#define CB   16        // col-blocks per tree
#define WC   16        // columns per block
#define RB   16        // row slots (256 threads = RB x WC)
#define CPAD 260       // padded row stride (float4-aligned)
#define NCTR (NT*32 + NT)   // levctr + poolctr ints

typedef unsigned long long ull;

__device__ __forceinline__ float sigm(float x){ return 1.f/(1.f + __expf(-x)); }

__device__ __forceinline__ ull pack2(float a, float b){
    union { float f[2]; ull u; } v; v.f[0] = a; v.f[1] = b; return v.u;
}
__device__ __forceinline__ void unpack2(ull u, float& a, float& b){
    union { ull u; float f[2]; } v; v.u = u; a = v.f[0]; b = v.f[1];
}
// relaxed agent-scope (device-coherent, cache-bypassing) accessors
__device__ __forceinline__ void st_dev(ull* p, ull v){
    __hip_atomic_store(p, v, __ATOMIC_RELAXED, __HIP_MEMORY_SCOPE_AGENT);
}
__device__ __forceinline__ ull ld_dev(const ull* p){
    return __hip_atomic_load(p, __ATOMIC_RELAXED, __HIP_MEMORY_SCOPE_AGENT);
}
__device__ __forceinline__ void st_devf(float* p, float v){
    __hip_atomic_store(p, v, __ATOMIC_RELAXED, __HIP_MEMORY_SCOPE_AGENT);
}
__device__ __forceinline__ float ld_devf(const float* p){
    return __hip_atomic_load(p, __ATOMIC_RELAXED, __HIP_MEMORY_SCOPE_AGENT);
}
__device__ __forceinline__ int ld_devi(const int* p){
    return __hip_atomic_load(p, __ATOMIC_RELAXED, __HIP_MEMORY_SCOPE_AGENT);
}

// ---------------------------------------------------------------------------
// Phase 1: ix/fx/ox/ux = concat(emb,rel) @ W_* (+ b_*); 8 nodes/block. FP32.
// Block 0 additionally zeroes the dataflow counters for tree_k.
// ---------------------------------------------------------------------------
__global__ __launch_bounds__(256) void phase1_k(
    const int* __restrict__ xs, const int* __restrict__ rels,
    const float* __restrict__ emb_W, const float* __restrict__ rel_W,
    const float* __restrict__ W_ix, const float* __restrict__ b_ix,
    const float* __restrict__ W_fx, const float* __restrict__ b_fx,
    const float* __restrict__ W_ox, const float* __restrict__ W_ux,
    float* __restrict__ ix, float* __restrict__ fx,
    float* __restrict__ ox, float* __restrict__ ux,
    int* __restrict__ ctrs)
{
    const int t = threadIdx.x;
    const int node0 = blockIdx.x * 8;
    __shared__ float xc[8][DIN];

    if (blockIdx.x == 0) {
        for (int i = t; i < NCTR; i += 256) ctrs[i] = 0;
    }

    #pragma unroll
    for (int j = 0; j < 8; ++j) {
        int n = node0 + j;
        if (t < DE) {
            long long w = (long long)xs[n];
            xc[j][t] = emb_W[w * DE + t];
        } else {
            long long r = (long long)rels[n];
            xc[j][t] = rel_W[r * DR + (t - DE)];
        }
    }
    __syncthreads();

    float ai[8], af[8], ao[8], au[8];
    const float bi  = b_ix[t];
    const float bfv = b_fx[t];
    #pragma unroll
    for (int j = 0; j < 8; ++j) { ai[j] = bi; af[j] = bfv; ao[j] = 0.f; au[j] = 0.f; }

    for (int k = 0; k < DIN; k += 4) {
        float wi[4], wf[4], wo[4], wu[4];
        #pragma unroll
        for (int q = 0; q < 4; ++q) {
            wi[q] = W_ix[(k+q)*HH + t];
            wf[q] = W_fx[(k+q)*HH + t];
            wo[q] = W_ox[(k+q)*HH + t];
            wu[q] = W_ux[(k+q)*HH + t];
        }
        #pragma unroll
        for (int j = 0; j < 8; ++j) {
            float4 xv = *(const float4*)&xc[j][k];
            ai[j] += xv.x*wi[0] + xv.y*wi[1] + xv.z*wi[2] + xv.w*wi[3];
            af[j] += xv.x*wf[0] + xv.y*wf[1] + xv.z*wf[2] + xv.w*wf[3];
            ao[j] += xv.x*wo[0] + xv.y*wo[1] + xv.z*wo[2] + xv.w*wo[3];
            au[j] += xv.x*wu[0] + xv.y*wu[1] + xv.z*wu[2] + xv.w*wu[3];
        }
    }
    #pragma unroll
    for (int j = 0; j < 8; ++j) {
        int n = node0 + j;
        ix[n*HH + t] = ai[j];
        fx[n*HH + t] = af[j];
        ox[n*HH + t] = ao[j];
        ux[n*HH + t] = au[j];
    }
}

// ---------------------------------------------------------------------------
// Fence-free dataflow recurrence: 256 blocks = 16 trees x 16 col-blocks.
// Cross-block data via relaxed agent-scope atomics; per-(tree,level) counters.
// Launched as a NORMAL kernel (round 9): no grid.sync anywhere; 256 blocks at
// 1 block/CU (157KB LDS) are hardware-co-resident on 256 CUs, so the dataflow
// cannot starve. Cooperative launch was only a co-residency belt-and-braces
// and is suspected to cost ~200us as a graph node.
// ---------------------------------------------------------------------------
__global__ __launch_bounds__(256, 1) void tree_k(
    const int* __restrict__ child_idx, const int* __restrict__ parent_idx,
    const int* __restrict__ node_height,
    const float* __restrict__ W_ih, const float* __restrict__ b_ih,
    const float* __restrict__ W_fh, const float* __restrict__ b_fh,
    const float* __restrict__ W_oh, const float* __restrict__ W_uh,
    const float* __restrict__ ix, const float* __restrict__ fx,
    const float* __restrict__ ox, const float* __restrict__ ux,
    ull* __restrict__ hx, int* __restrict__ levctr,
    float* __restrict__ poolbuf, int* __restrict__ poolctr,
    const float* __restrict__ W_out, const float* __restrict__ b_out,
    float* __restrict__ out)
{
    extern __shared__ float Wl[];            // [4][WC][CPAD] recurrent weights
    __shared__ float projL[4][SS][WC];       // ix,fx,ox,ux own-col slices
    __shared__ float cloc[SS][WC+1];         // cell state, never global
    __shared__ float hloc[SS][WC+1];         // own-col h, for pool + bulk store
    __shared__ float hstage[RB][CPAD];
    __shared__ float hsN[RB][CPAD];
    __shared__ float part[3*RB][WC+1];
    __shared__ float fcN[RB][WC+1];
    __shared__ float biasF[WC], biasI[WC];
    __shared__ int loff[SS+1], lcur[SS], llist[SS];
    __shared__ int lvoff[NLEV+1], lvcur[NLEV], lvnodes[SS];
    __shared__ int chs[RB], slts[RB], csum[RB+1], nodes_s[RB];
    __shared__ int s_maxH;

    const int t   = threadIdx.x;
    const int bid = blockIdx.x;
    // XCD-affine: tree b's 16 blocks all have bid % 8 == b % 8
    const int xcd  = bid & 7;
    const int idx  = bid >> 3;               // 0..31
    const int b    = xcd + 8 * (idx >> 4);   // tree
    const int cgp  = idx & 15;               // col group
    const int col0 = cgp * WC;
    const int cc   = t & 15;
    const int rr   = t >> 4;                 // 0..15

    // ---- build this tree's CSR + level lists in LDS (local node ids) ----
    if (t < SS)   lcur[t]  = 0;
    if (t < NLEV) lvcur[t] = 0;
    if (t == 0)   s_maxH   = 0;
    __syncthreads();
    if (t < TE) { int p = parent_idx[b*TE + t] - b*SS; atomicAdd(&lcur[p], 1); }
    if (t < SS) { int hg = node_height[b*SS + t]; atomicAdd(&lvcur[hg], 1); atomicMax(&s_maxH, hg); }
    __syncthreads();
    if (t == 0) {
        int off = 0;
        for (int i = 0; i < SS; ++i) { int v = lcur[i]; loff[i] = off; lcur[i] = off; off += v; }
        loff[SS] = off;
        off = 0;
        for (int l = 0; l < NLEV; ++l) { int v = lvcur[l]; lvoff[l] = off; lvcur[l] = off; off += v; }
        lvoff[NLEV] = off;
    }
    __syncthreads();
    if (t < TE) {
        int e = b*TE + t;
        int p = parent_idx[e] - b*SS;
        int pos = atomicAdd(&lcur[p], 1);
        llist[pos] = child_idx[e] - b*SS;
    }
    if (t < SS) {
        int hg = node_height[b*SS + t];
        int pos = atomicAdd(&lvcur[hg], 1);
        lvnodes[pos] = t;
    }

    // ---- load recurrent weight slices into LDS (fh, ih, oh, uh) ----
    {
        const float* Wm[4] = { W_fh, W_ih, W_oh, W_uh };
        for (int m = 0; m < 4; ++m) {
            float* dst = Wl + (m*WC + cc)*CPAD;
            const float* src = Wm[m] + col0 + cc;
            #pragma unroll 4
            for (int kb = 0; kb < 16; ++kb) {
                int k = kb*16 + rr;
                dst[k] = src[(long long)k*HH];
            }
        }
        if (t < WC) { biasF[t] = b_fh[col0+t]; biasI[t] = b_ih[col0+t]; }
    }

    // ---- preload proj slices into LDS ----
    {
        const float* P[4] = { ix, fx, ox, ux };
        for (int m = 0; m < 4; ++m) {
            #pragma unroll
            for (int base = 0; base < 512; base += 256) {
                int i = base + t;                 // float4 index
                int n = i >> 2, q = i & 3;
                *(float4*)&projL[m][n][q*4] =
                    *(const float4*)&P[m][(long long)(b*SS + n)*HH + col0 + q*4];
            }
        }
    }
    __syncthreads();

    // ---- bottom-up levels (0 = leaves) ----
    const int mH = s_maxH;
    for (int lev = 0; lev <= mH; ++lev) {
        if (lev > 0) {
            // all-thread poll: no barrier needed, each thread confirms
            while (ld_devi(&levctr[b*32 + lev - 1]) < CB)
                __builtin_amdgcn_s_sleep(1);
        }

        const int s0 = lvoff[lev], s1 = lvoff[lev+1];

        if (lev > 0 && s1 - s0 == 1) {
            // ================= fast path: single node =================
            const int n  = lvnodes[s0];
            const int off = loff[n];
            const int E  = loff[n+1] - off;
            if (E <= RB) {
                if (t < E)  chs[t] = llist[off + t];
                if (t < WC) fcN[0][t] = 0.f;
                __syncthreads();
                // stage all E child rows (packed coherent loads)
                for (int i = t; i < E*128; i += 256) {
                    int e = i >> 7, j = i & 127;
                    float a, bb;
                    unpack2(ld_dev(&hx[((long long)(b*SS + chs[e]))*HH/2 + j]), a, bb);
                    hstage[e][2*j]   = a;
                    hstage[e][2*j+1] = bb;
                }
                __syncthreads();
                // hsum into hsN[0]
                {
                    float s = 0.f;
                    for (int e = 0; e < E; ++e) s += hstage[e][t];
                    hsN[0][t] = s;
                }
                __syncthreads();
                // dots: rows 0..E-1 = f per edge, E..E+2 = i/o/u on hsum.
                // wave w owns row p0+w; lane: cc = t&15, ksl = (t>>4)&3 (dot-64);
                // reduce across ksl via shfl_xor (intra-wave, no barriers).
                const int wv   = t >> 6;
                const int ksl4 = (t >> 4) & 3;
                const int nrows = E + 3;
                for (int p0 = 0; p0 < nrows; p0 += 4) {
                    int r = p0 + wv;
                    float d = 0.f;
                    if (r < nrows) {
                        const float* hr = (r < E) ? hstage[r] : hsN[0];
                        int mat = (r < E) ? 0 : (1 + (r - E));
                        const float* wm = Wl + (mat*WC + cc)*CPAD + ksl4*64;
                        const float* hh = hr + ksl4*64;
                        #pragma unroll 8
                        for (int k = 0; k < 64; k += 4) {
                            float4 w4 = *(const float4*)(wm + k);
                            float4 h4 = *(const float4*)(hh + k);
                            d += w4.x*h4.x + w4.y*h4.y + w4.z*h4.z + w4.w*h4.w;
                        }
                    }
                    d += __shfl_xor(d, 16);
                    d += __shfl_xor(d, 32);
                    if (r < nrows && ksl4 == 0) {
                        if (r < E) {
                            float f = sigm(d + biasF[cc] + projL[1][n][cc]);
                            atomicAdd(&fcN[0][cc], f * cloc[chs[r]][cc]);
                        } else {
                            part[r - E][cc] = d;
                        }
                    }
                }
                __syncthreads();
                if (t < WC) {
                    float iv = sigm(projL[0][n][t] + part[0][t] + biasI[t]);
                    float ov = sigm(projL[2][n][t] + part[1][t]);
                    float uv = tanhf(projL[3][n][t] + part[2][t]);
                    float cv = iv*uv + fcN[0][t];
                    cloc[n][t] = cv;
                    hloc[n][t] = ov * tanhf(cv);
                }
                goto publish;   // common publish below
            }
            // E > RB: fall through to generic path
        }

        for (int cs = s0; cs < s1; cs += RB) {
            const int nbN = min(RB, s1 - cs);

            if (lev == 0) {
                if (rr < nbN) {
                    int n = lvnodes[cs + rr];
                    float iv = sigm(projL[0][n][cc] + biasI[cc]);
                    float ov = sigm(projL[2][n][cc]);
                    float uv = tanhf(projL[3][n][cc]);
                    float cv = iv * uv;
                    cloc[n][cc] = cv;
                    hloc[n][cc] = ov * tanhf(cv);
                }
                continue;
            }

            if (t < nbN) {
                int n = lvnodes[cs + t];
                nodes_s[t] = n;
                csum[t+1]  = loff[n+1] - loff[n];
            }
            if (t == 0) csum[0] = 0;
            __syncthreads();
            if (t == 0) for (int i = 1; i <= nbN; ++i) csum[i] += csum[i-1];
            for (int r2 = 0; r2 < nbN; ++r2) hsN[r2][t] = 0.f;
            fcN[rr][cc] = 0.f;
            __syncthreads();

            const int Ech = csum[nbN];
            for (int eb = 0; eb < Ech; eb += RB) {
                const int m = min(RB, Ech - eb);
                if (t < m) {
                    int e = eb + t;
                    int s2 = 0;
                    while (csum[s2+1] <= e) ++s2;
                    chs[t]  = llist[loff[nodes_s[s2]] + (e - csum[s2])];
                    slts[t] = s2;
                }
                __syncthreads();
                // stage child h rows: packed loads -> float4 LDS writes
                if (rr < m) {
                    const ull* src = hx + (((long long)(b*SS + chs[rr]))*HH + cc*16)/2;
                    float* dst = &hstage[rr][cc*16];
                    ull u[8];
                    #pragma unroll
                    for (int q = 0; q < 8; ++q) u[q] = ld_dev(&src[q]);
                    #pragma unroll
                    for (int q = 0; q < 4; ++q) {
                        float4 v;
                        unpack2(u[2*q],   v.x, v.y);
                        unpack2(u[2*q+1], v.z, v.w);
                        *(float4*)(dst + q*4) = v;
                    }
                }
                __syncthreads();
                for (int jj = 0; jj < m; ++jj)
                    hsN[slts[jj]][t] += hstage[jj][t];
                const int nb = (m<=1)?1:(m<=2)?2:(m<=4)?4:(m<=8)?8:16;
                {
                    int slot = rr % nb;
                    int ksl  = rr / nb;
                    float d = 0.f;
                    if (slot < m) {
                        const float* wf = Wl + (0*WC + cc)*CPAD;
                        const float* hr = hstage[slot];
                        int k0 = ksl * (16*nb), k1 = k0 + 16*nb;
                        for (int k = k0; k < k1; k += 4) {
                            float4 w4 = *(const float4*)(wf + k);
                            float4 h4 = *(const float4*)(hr + k);
                            d += w4.x*h4.x + w4.y*h4.y + w4.z*h4.z + w4.w*h4.w;
                        }
                    }
                    part[rr][cc] = d;
                }
                __syncthreads();
                if (rr < m) {
                    float d = 0.f;
                    for (int j = rr; j < RB; j += nb) d += part[j][cc];
                    float f = sigm(d + biasF[cc] + projL[1][nodes_s[slts[rr]]][cc]);
                    atomicAdd(&fcN[slts[rr]][cc], f * cloc[chs[rr]][cc]);
                }
                __syncthreads();
            }

            // i/o/u dots over hsum, depth-adaptive
            {
                const int nb2 = (nbN<=1)?1:(nbN<=2)?2:(nbN<=4)?4:(nbN<=8)?8:16;
                int slot = rr % nb2;
                int ksl  = rr / nb2;
                int k0 = ksl * (16*nb2), k1 = k0 + 16*nb2;
                for (int mat = 0; mat < 3; ++mat) {
                    float d = 0.f;
                    if (slot < nbN) {
                        const float* wm = Wl + ((1+mat)*WC + cc)*CPAD;
                        const float* hr = hsN[slot];
                        for (int k = k0; k < k1; k += 4) {
                            float4 w4 = *(const float4*)(wm + k);
                            float4 h4 = *(const float4*)(hr + k);
                            d += w4.x*h4.x + w4.y*h4.y + w4.z*h4.z + w4.w*h4.w;
                        }
                    }
                    part[mat*RB + rr][cc] = d;
                }
                __syncthreads();
                if (rr < nbN) {
                    float di = 0.f, dof = 0.f, du = 0.f;
                    for (int j = rr; j < RB; j += nb2) {
                        di  += part[0*RB + j][cc];
                        dof += part[1*RB + j][cc];
                        du  += part[2*RB + j][cc];
                    }
                    int n = nodes_s[rr];
                    float iv = sigm(projL[0][n][cc] + di + biasI[cc]);
                    float ov = sigm(projL[2][n][cc] + dof);
                    float uv = tanhf(projL[3][n][cc] + du);
                    float cv = iv*uv + fcN[rr][cc];
                    cloc[n][cc] = cv;
                    hloc[n][cc] = ov * tanhf(cv);
                }
                __syncthreads();
            }
        }

publish:
        // ---- bulk-publish this level's h (packed device-coherent stores) ----
        __syncthreads();
        {
            const int L = s1 - s0;
            for (int i = t; i < L*8; i += 256) {
                int n = lvnodes[s0 + (i >> 3)];
                int p = i & 7;
                ull u = pack2(hloc[n][2*p], hloc[n][2*p+1]);
                st_dev(&hx[(((long long)(b*SS + n))*HH + col0)/2 + p], u);
            }
        }
        __syncthreads();                     // drain stores before release
        if (t == 0) atomicAdd(&levctr[b*32 + lev], 1);
    }

    // ---- max-pool own columns from LDS, exchange, cgp==0 emits output ----
    {
        float mx = -3.4e38f;
        for (int s2 = rr; s2 < SS; s2 += RB)
            mx = fmaxf(mx, hloc[s2][cc]);
        part[rr][cc] = mx;
        __syncthreads();
        if (t < WC) {
            float m2 = part[0][t];
            #pragma unroll
            for (int r2 = 1; r2 < RB; ++r2) m2 = fmaxf(m2, part[r2][t]);
            st_devf(&poolbuf[b*HH + col0 + t], m2);
        }
        __syncthreads();                     // drain poolbuf stores
        if (t == 0) atomicAdd(&poolctr[b], 1);
    }
    if (cgp == 0) {
        while (ld_devi(&poolctr[b]) < CB)
            __builtin_amdgcn_s_sleep(1);
        float* pl = hstage[0];               // 260 >= 256 floats, reuse
        pl[t] = ld_devf(&poolbuf[b*HH + t]);
        __syncthreads();
        if (t < LOUT) {
            float acc = b_out[t];
            for (int k = 0; k < HH; ++k)
                acc += pl[k] * W_out[k*LOUT + t];
            out[b*LOUT + t] = acc;
        }
    }
}

// ---------------------------------------------------------------------------
extern "C" void kernel_launch(void* const* d_in, const int* in_sizes, int n_in,
                              void* d_out, int out_size, void* d_ws, size_t ws_size,
                              hipStream_t stream)
{
    const int* xs          = (const int*)d_in[0];
    const int* rels        = (const int*)d_in[1];
    const int* child_idx   = (const int*)d_in[2];
    const int* parent_idx  = (const int*)d_in[3];
    const int* node_height = (const int*)d_in[4];
    // d_in[5] = n_levels (hardcoded NLEV)
    const float* emb_W = (const float*)d_in[6];
    const float* rel_W = (const float*)d_in[7];
    const float* W_ix  = (const float*)d_in[8];
    const float* b_ix  = (const float*)d_in[9];
    const float* W_ih  = (const float*)d_in[10];
    const float* b_ih  = (const float*)d_in[11];
    const float* W_fx  = (const float*)d_in[12];
    const float* b_fx  = (const float*)d_in[13];
    const float* W_fh  = (const float*)d_in[14];
    const float* b_fh  = (const float*)d_in[15];
    const float* W_ox  = (const float*)d_in[16];
    const float* W_oh  = (const float*)d_in[17];
    const float* W_ux  = (const float*)d_in[18];
    const float* W_uh  = (const float*)d_in[19];
    const float* W_out = (const float*)d_in[20];
    const float* b_out = (const float*)d_in[21];

    const size_t NH = (size_t)NN * HH;
    float* ix = (float*)d_ws;
    float* fx = ix + NH;
    float* ox = fx + NH;
    float* ux = ox + NH;
    float* h  = ux + NH;                        // exchanged as ull pairs
    float* poolbuf = h + NH;                    // BB*HH floats
    int* levctr  = (int*)(poolbuf + BB*HH);     // NT*32
    int* poolctr = levctr + NT*32;              // NT

    phase1_k<<<NN/8, 256, 0, stream>>>(xs, rels, emb_W, rel_W,
                                       W_ix, b_ix, W_fx, b_fx, W_ox, W_ux,
                                       ix, fx, ox, ux, levctr);

    const unsigned int shmem = 4u * WC * CPAD * sizeof(float);   // 66560 B
    tree_k<<<dim3(NT*CB), dim3(256), shmem, stream>>>(
        child_idx, parent_idx, node_height,
        W_ih, b_ih, W_fh, b_fh, W_oh, W_uh,
        ix, fx, ox, ux,
        (ull*)h, levctr, poolbuf, poolctr,
        W_out, b_out, (float*)d_out);
}